// Round 11
// baseline (230.917 us; speedup 1.0000x reference)
//
#include <hip/hip_runtime.h>
#include <stdint.h>

#define BATCH 32
#define CIN   8
#define NCH   128   // 4*F_DIM
#define PP    128   // P
#define NSTRIP 8    // k1 strips per batch (16 p each)
#define KSTRIP 16   // k2 strips per batch (8 p each)

typedef __attribute__((ext_vector_type(8))) short    bf16x8;
typedef __attribute__((ext_vector_type(4))) float    f32x4;

__device__ __forceinline__ float bf2f(unsigned short u) {
    union { unsigned int i; float f; } x; x.i = ((unsigned int)u) << 16; return x.f;
}
__device__ __forceinline__ unsigned short f2bf(float f) {
    union { float f; unsigned int i; } x; x.f = f;
    unsigned int r = x.i + 0x7fffu + ((x.i >> 16) & 1u);
    return (unsigned short)(r >> 16);
}
__device__ __forceinline__ unsigned int pk2(float a, float b) {
    return (unsigned int)f2bf(a) | ((unsigned int)f2bf(b) << 16);
}

// Swizzled byte offset into a [128 rows][128 bf16] LDS tile (row = 256 B).
#define SWZB(row, cb) (((row) << 8) + ((cb) ^ (((row) & 7) << 4)))

// ---------------------------------------------------------------------------
// K1 (MFMA): RS1t[b][p][c] = sum_q t ; CS1p[b][strip][c][q] partial (R10).
// ---------------------------------------------------------------------------
__global__ __launch_bounds__(512, 4) void k1_sums(const float* __restrict__ phi,
        const float* __restrict__ W1, const float* __restrict__ b1,
        float* __restrict__ RS1t, float* __restrict__ CS1p) {
    __shared__ float cs_f[128 * 132];           // 67.6 KB, live only at flush
    __shared__ unsigned short phi_b[2][1024];   // [q][ci] bf16
    int bx = blockIdx.x;
    int b = bx >> 3, strip = bx & 7;
    int p0 = strip * 16;
    int tid = threadIdx.x;
    int wv = tid >> 6, l = tid & 63, lr = l & 15, lg = l >> 4;
    int c0 = wv * 16 + lg * 4;

    bf16x8 w1fr = {0, 0, 0, 0, 0, 0, 0, 0};
    if (lg == 0) {
        int cc = wv * 16 + lr;
        float4 wa = *(const float4*)(W1 + cc * 8);
        float4 wb = *(const float4*)(W1 + cc * 8 + 4);
        w1fr[0] = (short)f2bf(wa.x); w1fr[1] = (short)f2bf(wa.y);
        w1fr[2] = (short)f2bf(wa.z); w1fr[3] = (short)f2bf(wa.w);
        w1fr[4] = (short)f2bf(wb.x); w1fr[5] = (short)f2bf(wb.y);
        w1fr[6] = (short)f2bf(wb.z); w1fr[7] = (short)f2bf(wb.w);
    }
    f32x4 binit = {b1[c0], b1[c0 + 1], b1[c0 + 2], b1[c0 + 3]};
    if (tid < 128) {
        bf16x8 pv;
        #pragma unroll
        for (int ci = 0; ci < 8; ++ci)
            pv[ci] = (short)f2bf(phi[((size_t)(b * CIN + ci) * PP + p0) * PP + tid]);
        *(bf16x8*)(phi_b[0] + tid * 8) = pv;
    }
    __syncthreads();

    f32x4 cs_acc[8];
    #pragma unroll
    for (int i = 0; i < 8; ++i) { f32x4 z = {0.f, 0.f, 0.f, 0.f}; cs_acc[i] = z; }

    int cur = 0;
    for (int r = 0; r < 16; ++r) {
        int p = p0 + r;
        float pfv[8];
        if (r < 15 && tid < 128) {
            #pragma unroll
            for (int ci = 0; ci < 8; ++ci)
                pfv[ci] = phi[((size_t)(b * CIN + ci) * PP + p + 1) * PP + tid];
        }
        const unsigned short* pb = phi_b[cur];
        f32x4 rs4 = {0.f, 0.f, 0.f, 0.f};
        #pragma unroll
        for (int pt = 0; pt < 8; ++pt) {
            int pix = pt * 16 + lr;
            bf16x8 bfr1 = {0, 0, 0, 0, 0, 0, 0, 0};
            if (lg == 0) bfr1 = *(const bf16x8*)(pb + pix * 8);
            f32x4 a = __builtin_amdgcn_mfma_f32_16x16x32_bf16(w1fr, bfr1, binit, 0, 0, 0);
            f32x4 v = {fmaxf(a.x, 0.f), fmaxf(a.y, 0.f), fmaxf(a.z, 0.f), fmaxf(a.w, 0.f)};
            cs_acc[pt] += v;
            rs4 += v;
        }
        #pragma unroll
        for (int m = 1; m < 16; m <<= 1) {
            rs4.x += __shfl_xor(rs4.x, m);
            rs4.y += __shfl_xor(rs4.y, m);
            rs4.z += __shfl_xor(rs4.z, m);
            rs4.w += __shfl_xor(rs4.w, m);
        }
        if (lr == 0)
            *(f32x4*)(RS1t + ((size_t)b * PP + p) * NCH + c0) = rs4;
        if (r < 15 && tid < 128) {
            bf16x8 pv;
            #pragma unroll
            for (int ci = 0; ci < 8; ++ci) pv[ci] = (short)f2bf(pfv[ci]);
            *(bf16x8*)(phi_b[cur ^ 1] + tid * 8) = pv;
        }
        __syncthreads();
        cur ^= 1;
    }
    #pragma unroll
    for (int pt = 0; pt < 8; ++pt) {
        f32x4 v = cs_acc[pt];
        int q = pt * 16 + lr;
        cs_f[(c0 + 0) * 132 + q] = v.x;
        cs_f[(c0 + 1) * 132 + q] = v.y;
        cs_f[(c0 + 2) * 132 + q] = v.z;
        cs_f[(c0 + 3) * 132 + q] = v.w;
    }
    __syncthreads();
    float* dstp = CS1p + (size_t)(b * NSTRIP + strip) * NCH * PP;
    for (int k = tid; k < 16384; k += 512) {
        int cc = k >> 7, q = k & 127;
        dstp[k] = cs_f[cc * 132 + q];
    }
}

// ---------------------------------------------------------------------------
// K1b: Ap[b][o][q], Bqt[b][p][o] (with Cc folded in), W3bf (block 0).
// ---------------------------------------------------------------------------
__global__ __launch_bounds__(256) void k1b_planes(const float* __restrict__ W3,
        const float* __restrict__ b3, const float* __restrict__ RS1t,
        const float* __restrict__ CS1p, float* __restrict__ Ap,
        float* __restrict__ Bqt, unsigned short* __restrict__ W3bf) {
    int bx = blockIdx.x;
    int b = bx >> 2, og = bx & 3;
    int tid = threadIdx.x;
    __shared__ float cs_g[64][132];
    __shared__ float rs_g[64][132];
    __shared__ float s1_96[32];
    for (int k = tid; k < 64 * 128; k += 256) {
        int r = k >> 7, q = k & 127;
        int ch_c = (r < 32) ? (32 + r) : (64 + r);
        float s = 0.f;
        #pragma unroll
        for (int s8 = 0; s8 < NSTRIP; ++s8)
            s += CS1p[((size_t)(b * NSTRIP + s8) * NCH + ch_c) * PP + q];
        cs_g[r][q] = s;
    }
    for (int k = tid; k < 64 * 128; k += 256) {
        int p = k >> 6, r = k & 63;
        rs_g[r][p] = RS1t[((size_t)b * PP + p) * NCH + 64 + r];
    }
    __syncthreads();
    if (tid < 32) {
        float s = 0.f;
        for (int q = 0; q < 128; ++q) s += cs_g[32 + tid][q];
        s1_96[tid] = s;
    }
    int o = og * 32 + (tid >> 3), qh = tid & 7;
    {
        float wa[64];
        #pragma unroll
        for (int r = 0; r < 64; ++r)
            wa[r] = (r < 32) ? W3[o * NCH + 32 + r] * (1.f / 3.f)
                             : -W3[o * NCH + 64 + r] * (1.f / 9.f);
        #pragma unroll
        for (int j = 0; j < 4; ++j) {
            int q = qh * 16 + j * 4;
            float4 a = {0.f, 0.f, 0.f, 0.f};
            #pragma unroll
            for (int r = 0; r < 64; ++r) {
                float4 cv = *(const float4*)&cs_g[r][q];
                a.x = fmaf(wa[r], cv.x, a.x);
                a.y = fmaf(wa[r], cv.y, a.y);
                a.z = fmaf(wa[r], cv.z, a.z);
                a.w = fmaf(wa[r], cv.w, a.w);
            }
            *(float4*)&Ap[((size_t)b * NCH + o) * PP + q] = a;
        }
    }
    __syncthreads();
    float cc = b3[o];
    #pragma unroll
    for (int r = 0; r < 32; ++r)
        cc = fmaf(W3[o * NCH + 96 + r] * (1.f / 9.f), s1_96[r], cc);
    {
        float wb[64];
        #pragma unroll
        for (int r = 0; r < 64; ++r)
            wb[r] = (r < 32) ? W3[o * NCH + 64 + r] * (1.f / 3.f)
                             : -W3[o * NCH + 64 + r] * (1.f / 9.f);
        #pragma unroll
        for (int j = 0; j < 4; ++j) {
            int p4 = qh * 16 + j * 4;
            float4 a = {0.f, 0.f, 0.f, 0.f};
            #pragma unroll
            for (int r = 0; r < 64; ++r) {
                float4 rv = *(const float4*)&rs_g[r][p4];
                a.x = fmaf(wb[r], rv.x, a.x);
                a.y = fmaf(wb[r], rv.y, a.y);
                a.z = fmaf(wb[r], rv.z, a.z);
                a.w = fmaf(wb[r], rv.w, a.w);
            }
            Bqt[((size_t)b * PP + p4 + 0) * NCH + o] = a.x + cc;
            Bqt[((size_t)b * PP + p4 + 1) * NCH + o] = a.y + cc;
            Bqt[((size_t)b * PP + p4 + 2) * NCH + o] = a.z + cc;
            Bqt[((size_t)b * PP + p4 + 3) * NCH + o] = a.w + cc;
        }
    }
    if (bx == 0) {
        for (int i = 0; i < 16; ++i) {
            int k = tid + i * 256;
            float4 w = *(const float4*)(W3 + k * 4);
            int c0 = (k * 4) & 127;
            float sc = (c0 < 32) ? 1.f : ((c0 < 96) ? (-1.f / 3.f) : (1.f / 9.f));
            unsigned int lo = pk2(w.x * sc, w.y * sc);
            unsigned int hi = pk2(w.z * sc, w.w * sc);
            uint2 u = {lo, hi};
            *(uint2*)(W3bf + k * 4) = u;
        }
    }
}

// ---------------------------------------------------------------------------
// K2: W3 fragments REGISTER-HOSTED (loaded once from global), separate v_l
// buffer -> only 2 barriers per row, LDS ops/wave/row 56 -> 24.
// Grid 32 b x 16 strips, 512 threads, launch_bounds(512,2).
// ---------------------------------------------------------------------------
__global__ __launch_bounds__(512, 2) void k2_mfma(const float* __restrict__ phi,
        const float* __restrict__ W1, const float* __restrict__ b1,
        const unsigned short* __restrict__ W3bf,
        const float* __restrict__ Ap, const float* __restrict__ Bqt,
        unsigned short* __restrict__ v2) {
    int bx = blockIdx.x;
    int b = bx >> 4, strip = bx & 15;
    int p0 = strip * 8;
    __shared__ unsigned short t_l[16384];       // GEMM1 out [pix][c] swizzled
    __shared__ unsigned short v_l[16384];       // GEMM2 out [o][q] swizzled
    __shared__ unsigned short phi_b[2][1024];
    __shared__ float BC_l[2][128];
    int tid = threadIdx.x;
    int wv = tid >> 6, l = tid & 63, lr = l & 15, lg = l >> 4;
    int q0 = wv * 16 + lg * 4;
    int c0 = q0;

    // W3' fragments: register-hosted, one-time global load (L2-served).
    bf16x8 w3r[8][4];
    #pragma unroll
    for (int nt = 0; nt < 8; ++nt)
        #pragma unroll
        for (int ks = 0; ks < 4; ++ks)
            w3r[nt][ks] = *(const bf16x8*)(W3bf + (size_t)(nt * 16 + lr) * NCH + ks * 32 + lg * 8);
    bf16x8 w1fr = {0, 0, 0, 0, 0, 0, 0, 0};
    if (lg == 0) {
        int cc = wv * 16 + lr;
        float4 wa = *(const float4*)(W1 + cc * 8);
        float4 wb = *(const float4*)(W1 + cc * 8 + 4);
        w1fr[0] = (short)f2bf(wa.x); w1fr[1] = (short)f2bf(wa.y);
        w1fr[2] = (short)f2bf(wa.z); w1fr[3] = (short)f2bf(wa.w);
        w1fr[4] = (short)f2bf(wb.x); w1fr[5] = (short)f2bf(wb.y);
        w1fr[6] = (short)f2bf(wb.z); w1fr[7] = (short)f2bf(wb.w);
    }
    f32x4 binit = {b1[c0], b1[c0 + 1], b1[c0 + 2], b1[c0 + 3]};
    f32x4 apr[8];
    #pragma unroll
    for (int nt = 0; nt < 8; ++nt)
        apr[nt] = *(const f32x4*)(Ap + ((size_t)(b * NCH + nt * 16 + lr)) * PP + q0);
    if (tid < 128) {
        bf16x8 pv;
        #pragma unroll
        for (int ci = 0; ci < 8; ++ci)
            pv[ci] = (short)f2bf(phi[((size_t)(b * CIN + ci) * PP + p0) * PP + tid]);
        *(bf16x8*)(phi_b[0] + tid * 8) = pv;
        BC_l[0][tid] = Bqt[((size_t)b * PP + p0) * NCH + tid];
    }
    __syncthreads();

    for (int r = 0; r < 8; ++r) {
        int cur = r & 1, nxt = cur ^ 1;
        int p = p0 + r;
        float pfv[8]; float bcn = 0.f;
        if (r < 7 && tid < 128) {
            #pragma unroll
            for (int ci = 0; ci < 8; ++ci)
                pfv[ci] = phi[((size_t)(b * CIN + ci) * PP + p + 1) * PP + tid];
            bcn = Bqt[((size_t)b * PP + p + 1) * NCH + tid];
        }
        // GEMM1 -> t_l
        const unsigned short* pb = phi_b[cur];
        #pragma unroll
        for (int pt = 0; pt < 8; ++pt) {
            int pix = pt * 16 + lr;
            bf16x8 bfr1 = {0, 0, 0, 0, 0, 0, 0, 0};
            if (lg == 0) bfr1 = *(const bf16x8*)(pb + pix * 8);
            f32x4 a = __builtin_amdgcn_mfma_f32_16x16x32_bf16(w1fr, bfr1, binit, 0, 0, 0);
            uint2 u;
            u.x = pk2(fmaxf(a.x, 0.f), fmaxf(a.y, 0.f));
            u.y = pk2(fmaxf(a.z, 0.f), fmaxf(a.w, 0.f));
            *(uint2*)((char*)t_l + SWZB(pix, c0 * 2)) = u;
        }
        __syncthreads();                 // (A) t_l ready; prev v_l stores done
        bf16x8 afr[4];
        #pragma unroll
        for (int ks = 0; ks < 4; ++ks)
            afr[ks] = *(const bf16x8*)((char*)t_l + SWZB(wv * 16 + lr, ks * 64 + lg * 16));
        // GEMM2 (register W3) -> v_l
        #pragma unroll
        for (int nt = 0; nt < 8; ++nt) {
            int o = nt * 16 + lr;
            f32x4 acc = apr[nt] + BC_l[cur][o];
            #pragma unroll
            for (int ks = 0; ks < 4; ++ks)
                acc = __builtin_amdgcn_mfma_f32_16x16x32_bf16(afr[ks], w3r[nt][ks], acc, 0, 0, 0);
            uint2 u;
            u.x = pk2(fmaxf(acc.x, 0.f), fmaxf(acc.y, 0.f));
            u.y = pk2(fmaxf(acc.z, 0.f), fmaxf(acc.w, 0.f));
            *(uint2*)((char*)v_l + SWZB(o, q0 * 2)) = u;
        }
        if (r < 7 && tid < 128) {
            bf16x8 pv;
            #pragma unroll
            for (int ci = 0; ci < 8; ++ci) pv[ci] = (short)f2bf(pfv[ci]);
            *(bf16x8*)(phi_b[nxt] + tid * 8) = pv;
            BC_l[nxt][tid] = bcn;
        }
        __syncthreads();                 // (C) v_l + next phi ready; t_l afr-reads done
        #pragma unroll
        for (int i = 0; i < 4; ++i) {
            int k = tid + i * 512;
            int o = k >> 4, j = k & 15;
            bf16x8 v = *(const bf16x8*)((char*)v_l + SWZB(o, j * 16));
            *(bf16x8*)(v2 + ((size_t)(b * NCH + o) * PP + p) * PP + j * 8) = v;
        }
        // no barrier: next v_l write is after (A) of row r+1
    }
}

// ---------------------------------------------------------------------------
// K3: two-pass (2nd pass L2-hot), REGISTER sums during pass 1.
// One block per (b,ch), 256 threads, ~17 KB LDS -> 8 blocks/CU.
// ---------------------------------------------------------------------------
__global__ __launch_bounds__(256) void k3_out(const unsigned short* __restrict__ v2,
        float* __restrict__ out) {
    int bx = blockIdx.x;
    int b = bx >> 7, ch = bx & 127;
    int g = ch >> 5;
    __shared__ float rsp[128][17];
    __shared__ float csp[16][132];
    __shared__ float rs_l[128], cs_l[128];
    __shared__ float s_sh;
    int tid = threadIdx.x;
    size_t base = (size_t)(b * NCH + ch) * (PP * PP);
    const unsigned short* src = v2 + base;

    int pc = tid >> 4, qc = tid & 15;
    float cs8[8];
    #pragma unroll
    for (int e = 0; e < 8; ++e) cs8[e] = 0.f;
    #pragma unroll
    for (int i = 0; i < 8; ++i) {
        int pr = pc * 8 + i;
        bf16x8 u = *(const bf16x8*)(src + pr * PP + qc * 8);
        float rp = 0.f;
        #pragma unroll
        for (int e = 0; e < 8; ++e) {
            float v = bf2f((unsigned short)u[e]);
            cs8[e] += v;
            rp += v;
        }
        rsp[pr][qc] = rp;
    }
    f32x4 clo = {cs8[0], cs8[1], cs8[2], cs8[3]};
    f32x4 chi = {cs8[4], cs8[5], cs8[6], cs8[7]};
    *(f32x4*)&csp[pc][qc * 8]     = clo;
    *(f32x4*)&csp[pc][qc * 8 + 4] = chi;
    __syncthreads();
    if (tid < 128) {
        float s = 0.f;
        #pragma unroll
        for (int j = 0; j < 16; ++j) s += rsp[tid][j];
        rs_l[tid] = s;
    } else {
        int q = tid - 128;
        float s = 0.f;
        #pragma unroll
        for (int i = 0; i < 16; ++i) s += csp[i][q];
        cs_l[q] = s;
    }
    __syncthreads();
    if (tid < 64) {
        float s = rs_l[tid] + rs_l[tid + 64];
        #pragma unroll
        for (int off = 32; off > 0; off >>= 1) s += __shfl_down(s, off);
        if (tid == 0) s_sh = s;
    }
    __syncthreads();
    float stot = s_sh;
    float* dst = out + base;
    #pragma unroll
    for (int i = 0; i < 8; ++i) {
        int k = tid + i * 256;
        int pr = k >> 4, q0 = (k & 15) * 8;
        bf16x8 u = *(const bf16x8*)(src + pr * PP + q0);   // L2-hot re-read
        float rp = rs_l[pr];
        float o8[8];
        #pragma unroll
        for (int e = 0; e < 8; ++e) {
            float v = bf2f((unsigned short)u[e]);
            float cq = cs_l[q0 + e];
            float r;
            if (g == 0)      r = v;
            else if (g == 1) r = (cq - v) * (1.f / 3.f);
            else if (g == 2) r = (rp - v) * (1.f / 3.f);
            else             r = ((stot - rp) - cq + v) * (1.f / 9.f);
            o8[e] = r;
        }
        f32x4 lo = {o8[0], o8[1], o8[2], o8[3]};
        f32x4 hi = {o8[4], o8[5], o8[6], o8[7]};
        *(f32x4*)(dst + pr * PP + q0)     = lo;
        *(f32x4*)(dst + pr * PP + q0 + 4) = hi;
    }
}

// ---------------------------------------------------------------------------
extern "C" void kernel_launch(void* const* d_in, const int* in_sizes, int n_in,
                              void* d_out, int out_size, void* d_ws, size_t ws_size,
                              hipStream_t stream) {
    (void)in_sizes; (void)n_in; (void)out_size; (void)ws_size;
    const float* phi = (const float*)d_in[0];
    const float* W1  = (const float*)d_in[1];
    const float* b1  = (const float*)d_in[2];
    const float* W3  = (const float*)d_in[3];
    const float* b3  = (const float*)d_in[4];
    float* out = (float*)d_out;

    char* ws = (char*)d_ws;
    size_t off = 0;
    unsigned short* v2 = (unsigned short*)(ws + off); off += (size_t)BATCH * NCH * PP * PP * 2; // 134 MB
    float* RS1t = (float*)(ws + off); off += (size_t)BATCH * NCH * PP * 4;            // 2 MB
    float* CS1p = (float*)(ws + off); off += (size_t)BATCH * NSTRIP * NCH * PP * 4;   // 16 MB
    float* Ap   = (float*)(ws + off); off += (size_t)BATCH * NCH * PP * 4;            // 8 MB
    float* Bqt  = (float*)(ws + off); off += (size_t)BATCH * NCH * PP * 4;            // 8 MB
    unsigned short* W3bf = (unsigned short*)(ws + off); off += (size_t)NCH * NCH * 2; // 32 KB

    k1_sums<<<BATCH * NSTRIP, 512, 0, stream>>>(phi, W1, b1, RS1t, CS1p);
    k1b_planes<<<BATCH * 4, 256, 0, stream>>>(W3, b3, RS1t, CS1p, Ap, Bqt, W3bf);
    k2_mfma<<<BATCH * KSTRIP, 512, 0, stream>>>(phi, W1, b1, W3bf, Ap, Bqt, v2);
    k3_out<<<BATCH * NCH, 256, 0, stream>>>(v2, out);
}

// Round 12
// 221.483 us; speedup vs baseline: 1.0426x; 1.0426x over previous
//
#include <hip/hip_runtime.h>
#include <stdint.h>

#define BATCH 32
#define CIN   8
#define NCH   128   // 4*F_DIM
#define PP    128   // P
#define NSTRIP 8    // k1 strips per batch (16 p each)
#define KSTRIP 16   // k2 strips per batch (8 p each)

typedef __attribute__((ext_vector_type(8))) short    bf16x8;
typedef __attribute__((ext_vector_type(4))) float    f32x4;

__device__ __forceinline__ float bf2f(unsigned short u) {
    union { unsigned int i; float f; } x; x.i = ((unsigned int)u) << 16; return x.f;
}
__device__ __forceinline__ unsigned short f2bf(float f) {
    union { float f; unsigned int i; } x; x.f = f;
    unsigned int r = x.i + 0x7fffu + ((x.i >> 16) & 1u);
    return (unsigned short)(r >> 16);
}
__device__ __forceinline__ unsigned int pk2(float a, float b) {
    return (unsigned int)f2bf(a) | ((unsigned int)f2bf(b) << 16);
}

// Swizzled byte offset into a [128 rows][128 bf16] LDS tile (row = 256 B).
#define SWZB(row, cb) (((row) << 8) + ((cb) ^ (((row) & 7) << 4)))

// ---------------------------------------------------------------------------
// K1 (MFMA): RS1t[b][p][c] = sum_q t ; CS1p[b][strip][c][q] partial (R10).
// ---------------------------------------------------------------------------
__global__ __launch_bounds__(512, 4) void k1_sums(const float* __restrict__ phi,
        const float* __restrict__ W1, const float* __restrict__ b1,
        float* __restrict__ RS1t, float* __restrict__ CS1p) {
    __shared__ float cs_f[128 * 132];           // 67.6 KB, live only at flush
    __shared__ unsigned short phi_b[2][1024];   // [q][ci] bf16
    int bx = blockIdx.x;
    int b = bx >> 3, strip = bx & 7;
    int p0 = strip * 16;
    int tid = threadIdx.x;
    int wv = tid >> 6, l = tid & 63, lr = l & 15, lg = l >> 4;
    int c0 = wv * 16 + lg * 4;

    bf16x8 w1fr = {0, 0, 0, 0, 0, 0, 0, 0};
    if (lg == 0) {
        int cc = wv * 16 + lr;
        float4 wa = *(const float4*)(W1 + cc * 8);
        float4 wb = *(const float4*)(W1 + cc * 8 + 4);
        w1fr[0] = (short)f2bf(wa.x); w1fr[1] = (short)f2bf(wa.y);
        w1fr[2] = (short)f2bf(wa.z); w1fr[3] = (short)f2bf(wa.w);
        w1fr[4] = (short)f2bf(wb.x); w1fr[5] = (short)f2bf(wb.y);
        w1fr[6] = (short)f2bf(wb.z); w1fr[7] = (short)f2bf(wb.w);
    }
    f32x4 binit = {b1[c0], b1[c0 + 1], b1[c0 + 2], b1[c0 + 3]};
    if (tid < 128) {
        bf16x8 pv;
        #pragma unroll
        for (int ci = 0; ci < 8; ++ci)
            pv[ci] = (short)f2bf(phi[((size_t)(b * CIN + ci) * PP + p0) * PP + tid]);
        *(bf16x8*)(phi_b[0] + tid * 8) = pv;
    }
    __syncthreads();

    f32x4 cs_acc[8];
    #pragma unroll
    for (int i = 0; i < 8; ++i) { f32x4 z = {0.f, 0.f, 0.f, 0.f}; cs_acc[i] = z; }

    int cur = 0;
    for (int r = 0; r < 16; ++r) {
        int p = p0 + r;
        float pfv[8];
        if (r < 15 && tid < 128) {
            #pragma unroll
            for (int ci = 0; ci < 8; ++ci)
                pfv[ci] = phi[((size_t)(b * CIN + ci) * PP + p + 1) * PP + tid];
        }
        const unsigned short* pb = phi_b[cur];
        f32x4 rs4 = {0.f, 0.f, 0.f, 0.f};
        #pragma unroll
        for (int pt = 0; pt < 8; ++pt) {
            int pix = pt * 16 + lr;
            bf16x8 bfr1 = {0, 0, 0, 0, 0, 0, 0, 0};
            if (lg == 0) bfr1 = *(const bf16x8*)(pb + pix * 8);
            f32x4 a = __builtin_amdgcn_mfma_f32_16x16x32_bf16(w1fr, bfr1, binit, 0, 0, 0);
            f32x4 v = {fmaxf(a.x, 0.f), fmaxf(a.y, 0.f), fmaxf(a.z, 0.f), fmaxf(a.w, 0.f)};
            cs_acc[pt] += v;
            rs4 += v;
        }
        #pragma unroll
        for (int m = 1; m < 16; m <<= 1) {
            rs4.x += __shfl_xor(rs4.x, m);
            rs4.y += __shfl_xor(rs4.y, m);
            rs4.z += __shfl_xor(rs4.z, m);
            rs4.w += __shfl_xor(rs4.w, m);
        }
        if (lr == 0)
            *(f32x4*)(RS1t + ((size_t)b * PP + p) * NCH + c0) = rs4;
        if (r < 15 && tid < 128) {
            bf16x8 pv;
            #pragma unroll
            for (int ci = 0; ci < 8; ++ci) pv[ci] = (short)f2bf(pfv[ci]);
            *(bf16x8*)(phi_b[cur ^ 1] + tid * 8) = pv;
        }
        __syncthreads();
        cur ^= 1;
    }
    #pragma unroll
    for (int pt = 0; pt < 8; ++pt) {
        f32x4 v = cs_acc[pt];
        int q = pt * 16 + lr;
        cs_f[(c0 + 0) * 132 + q] = v.x;
        cs_f[(c0 + 1) * 132 + q] = v.y;
        cs_f[(c0 + 2) * 132 + q] = v.z;
        cs_f[(c0 + 3) * 132 + q] = v.w;
    }
    __syncthreads();
    float* dstp = CS1p + (size_t)(b * NSTRIP + strip) * NCH * PP;
    for (int k = tid; k < 16384; k += 512) {
        int cc = k >> 7, q = k & 127;
        dstp[k] = cs_f[cc * 132 + q];
    }
}

// ---------------------------------------------------------------------------
// K1b: Ap[b][o][q], Bqt[b][p][o] (with Cc folded in), W3bf (block 0).
// ---------------------------------------------------------------------------
__global__ __launch_bounds__(256) void k1b_planes(const float* __restrict__ W3,
        const float* __restrict__ b3, const float* __restrict__ RS1t,
        const float* __restrict__ CS1p, float* __restrict__ Ap,
        float* __restrict__ Bqt, unsigned short* __restrict__ W3bf) {
    int bx = blockIdx.x;
    int b = bx >> 2, og = bx & 3;
    int tid = threadIdx.x;
    __shared__ float cs_g[64][132];
    __shared__ float rs_g[64][132];
    __shared__ float s1_96[32];
    for (int k = tid; k < 64 * 128; k += 256) {
        int r = k >> 7, q = k & 127;
        int ch_c = (r < 32) ? (32 + r) : (64 + r);
        float s = 0.f;
        #pragma unroll
        for (int s8 = 0; s8 < NSTRIP; ++s8)
            s += CS1p[((size_t)(b * NSTRIP + s8) * NCH + ch_c) * PP + q];
        cs_g[r][q] = s;
    }
    for (int k = tid; k < 64 * 128; k += 256) {
        int p = k >> 6, r = k & 63;
        rs_g[r][p] = RS1t[((size_t)b * PP + p) * NCH + 64 + r];
    }
    __syncthreads();
    if (tid < 32) {
        float s = 0.f;
        for (int q = 0; q < 128; ++q) s += cs_g[32 + tid][q];
        s1_96[tid] = s;
    }
    int o = og * 32 + (tid >> 3), qh = tid & 7;
    {
        float wa[64];
        #pragma unroll
        for (int r = 0; r < 64; ++r)
            wa[r] = (r < 32) ? W3[o * NCH + 32 + r] * (1.f / 3.f)
                             : -W3[o * NCH + 64 + r] * (1.f / 9.f);
        #pragma unroll
        for (int j = 0; j < 4; ++j) {
            int q = qh * 16 + j * 4;
            float4 a = {0.f, 0.f, 0.f, 0.f};
            #pragma unroll
            for (int r = 0; r < 64; ++r) {
                float4 cv = *(const float4*)&cs_g[r][q];
                a.x = fmaf(wa[r], cv.x, a.x);
                a.y = fmaf(wa[r], cv.y, a.y);
                a.z = fmaf(wa[r], cv.z, a.z);
                a.w = fmaf(wa[r], cv.w, a.w);
            }
            *(float4*)&Ap[((size_t)b * NCH + o) * PP + q] = a;
        }
    }
    __syncthreads();
    float cc = b3[o];
    #pragma unroll
    for (int r = 0; r < 32; ++r)
        cc = fmaf(W3[o * NCH + 96 + r] * (1.f / 9.f), s1_96[r], cc);
    {
        float wb[64];
        #pragma unroll
        for (int r = 0; r < 64; ++r)
            wb[r] = (r < 32) ? W3[o * NCH + 64 + r] * (1.f / 3.f)
                             : -W3[o * NCH + 64 + r] * (1.f / 9.f);
        #pragma unroll
        for (int j = 0; j < 4; ++j) {
            int p4 = qh * 16 + j * 4;
            float4 a = {0.f, 0.f, 0.f, 0.f};
            #pragma unroll
            for (int r = 0; r < 64; ++r) {
                float4 rv = *(const float4*)&rs_g[r][p4];
                a.x = fmaf(wb[r], rv.x, a.x);
                a.y = fmaf(wb[r], rv.y, a.y);
                a.z = fmaf(wb[r], rv.z, a.z);
                a.w = fmaf(wb[r], rv.w, a.w);
            }
            Bqt[((size_t)b * PP + p4 + 0) * NCH + o] = a.x + cc;
            Bqt[((size_t)b * PP + p4 + 1) * NCH + o] = a.y + cc;
            Bqt[((size_t)b * PP + p4 + 2) * NCH + o] = a.z + cc;
            Bqt[((size_t)b * PP + p4 + 3) * NCH + o] = a.w + cc;
        }
    }
    if (bx == 0) {
        for (int i = 0; i < 16; ++i) {
            int k = tid + i * 256;
            float4 w = *(const float4*)(W3 + k * 4);
            int c0 = (k * 4) & 127;
            float sc = (c0 < 32) ? 1.f : ((c0 < 96) ? (-1.f / 3.f) : (1.f / 9.f));
            unsigned int lo = pk2(w.x * sc, w.y * sc);
            unsigned int hi = pk2(w.z * sc, w.w * sc);
            uint2 u = {lo, hi};
            *(uint2*)(W3bf + k * 4) = u;
        }
    }
}

// ---------------------------------------------------------------------------
// K2: R10 slim MFMA kernel + in-store-loop sums (row-invariant lane->(o,q)):
//   i==1 chunk -> cs1 (ch 32+g16), i==2 -> rsum (ch 64+g16),
//   i==3 -> cs3 + rsum (ch 96+g16).  16 extra VGPR, no extra barriers.
// RSvT[b][jr][p] per row (jr = o-64); CSp strip partials at kernel end.
// Plain launch_bounds(512): compiler free on VGPR (no forced spill).
// ---------------------------------------------------------------------------
__global__ __launch_bounds__(512) void k2_mfma(const float* __restrict__ phi,
        const float* __restrict__ W1, const float* __restrict__ b1,
        const unsigned short* __restrict__ W3bf,
        const float* __restrict__ Ap, const float* __restrict__ Bqt,
        unsigned short* __restrict__ v2, float* __restrict__ RSvT,
        float* __restrict__ CSp) {
    int bx = blockIdx.x;
    int b = bx >> 4, strip = bx & 15;
    int p0 = strip * 8;
    __shared__ unsigned short w3_l[16384];
    __shared__ unsigned short t_l[16384];
    __shared__ unsigned short phi_b[2][1024];
    __shared__ float BC_l[2][128];
    int tid = threadIdx.x;
    int wv = tid >> 6, l = tid & 63, lr = l & 15, lg = l >> 4;
    int q0 = wv * 16 + lg * 4;
    int g16 = tid >> 4, jj = tid & 15;

    #pragma unroll
    for (int i = 0; i < 4; ++i) {
        int k = tid + i * 512;
        int o = k >> 4, cb = (k & 15) * 16;
        bf16x8 v = *(const bf16x8*)(W3bf + k * 8);
        *(bf16x8*)((char*)w3_l + SWZB(o, cb)) = v;
    }
    bf16x8 w1fr = {0, 0, 0, 0, 0, 0, 0, 0};
    if (lg == 0) {
        int cc = wv * 16 + lr;
        float4 wa = *(const float4*)(W1 + cc * 8);
        float4 wb = *(const float4*)(W1 + cc * 8 + 4);
        w1fr[0] = (short)f2bf(wa.x); w1fr[1] = (short)f2bf(wa.y);
        w1fr[2] = (short)f2bf(wa.z); w1fr[3] = (short)f2bf(wa.w);
        w1fr[4] = (short)f2bf(wb.x); w1fr[5] = (short)f2bf(wb.y);
        w1fr[6] = (short)f2bf(wb.z); w1fr[7] = (short)f2bf(wb.w);
    }
    int c0 = wv * 16 + lg * 4;
    f32x4 binit = {b1[c0], b1[c0 + 1], b1[c0 + 2], b1[c0 + 3]};
    f32x4 apr[8];
    #pragma unroll
    for (int nt = 0; nt < 8; ++nt)
        apr[nt] = *(const f32x4*)(Ap + ((size_t)(b * NCH + nt * 16 + lr)) * PP + q0);
    if (tid < 128) {
        bf16x8 pv;
        #pragma unroll
        for (int ci = 0; ci < 8; ++ci)
            pv[ci] = (short)f2bf(phi[((size_t)(b * CIN + ci) * PP + p0) * PP + tid]);
        *(bf16x8*)(phi_b[0] + tid * 8) = pv;
        BC_l[0][tid] = Bqt[((size_t)b * PP + p0) * NCH + tid];
    }
    __syncthreads();

    float cs1[8], cs3[8];
    #pragma unroll
    for (int e = 0; e < 8; ++e) { cs1[e] = 0.f; cs3[e] = 0.f; }

    for (int r = 0; r < 8; ++r) {
        int cur = r & 1, nxt = cur ^ 1;
        int p = p0 + r;
        float pfv[8]; float bcn = 0.f;
        if (r < 7 && tid < 128) {
            #pragma unroll
            for (int ci = 0; ci < 8; ++ci)
                pfv[ci] = phi[((size_t)(b * CIN + ci) * PP + p + 1) * PP + tid];
            bcn = Bqt[((size_t)b * PP + p + 1) * NCH + tid];
        }
        const unsigned short* pb = phi_b[cur];
        #pragma unroll
        for (int pt = 0; pt < 8; ++pt) {
            int pix = pt * 16 + lr;
            bf16x8 bfr1 = {0, 0, 0, 0, 0, 0, 0, 0};
            if (lg == 0) bfr1 = *(const bf16x8*)(pb + pix * 8);
            f32x4 a = __builtin_amdgcn_mfma_f32_16x16x32_bf16(w1fr, bfr1, binit, 0, 0, 0);
            uint2 u;
            u.x = pk2(fmaxf(a.x, 0.f), fmaxf(a.y, 0.f));
            u.y = pk2(fmaxf(a.z, 0.f), fmaxf(a.w, 0.f));
            *(uint2*)((char*)t_l + SWZB(pix, c0 * 2)) = u;
        }
        __syncthreads();                     // (A) t_l ready
        bf16x8 afr[4];
        #pragma unroll
        for (int ks = 0; ks < 4; ++ks)
            afr[ks] = *(const bf16x8*)((char*)t_l + SWZB(wv * 16 + lr, ks * 64 + lg * 16));
        __syncthreads();                     // (B) afr reads done -> t_l reusable
        #pragma unroll
        for (int nt = 0; nt < 8; ++nt) {
            int o = nt * 16 + lr;
            bf16x8 bfr[4];
            #pragma unroll
            for (int ks = 0; ks < 4; ++ks)
                bfr[ks] = *(const bf16x8*)((char*)w3_l + SWZB(o, ks * 64 + lg * 16));
            f32x4 acc = apr[nt] + BC_l[cur][o];
            #pragma unroll
            for (int ks = 0; ks < 4; ++ks)
                acc = __builtin_amdgcn_mfma_f32_16x16x32_bf16(afr[ks], bfr[ks], acc, 0, 0, 0);
            uint2 u;
            u.x = pk2(fmaxf(acc.x, 0.f), fmaxf(acc.y, 0.f));
            u.y = pk2(fmaxf(acc.z, 0.f), fmaxf(acc.w, 0.f));
            *(uint2*)((char*)t_l + SWZB(o, q0 * 2)) = u;
        }
        if (r < 7 && tid < 128) {
            bf16x8 pv;
            #pragma unroll
            for (int ci = 0; ci < 8; ++ci) pv[ci] = (short)f2bf(pfv[ci]);
            *(bf16x8*)(phi_b[nxt] + tid * 8) = pv;
            BC_l[nxt][tid] = bcn;
        }
        __syncthreads();                     // (C) v_l complete + next phi ready
        // store + in-flight sums (lane->(o,q) row-invariant)
        float rsum2 = 0.f, rsum3 = 0.f;
        #pragma unroll
        for (int i = 0; i < 4; ++i) {
            int k = tid + i * 512;
            int o = k >> 4, j = k & 15;
            bf16x8 v = *(const bf16x8*)((char*)t_l + SWZB(o, j * 16));
            *(bf16x8*)(v2 + ((size_t)(b * NCH + o) * PP + p) * PP + j * 8) = v;
            if (i == 1) {
                #pragma unroll
                for (int e = 0; e < 8; ++e) cs1[e] += bf2f((unsigned short)v[e]);
            } else if (i == 2) {
                #pragma unroll
                for (int e = 0; e < 8; ++e) rsum2 += bf2f((unsigned short)v[e]);
            } else if (i == 3) {
                #pragma unroll
                for (int e = 0; e < 8; ++e) {
                    float f = bf2f((unsigned short)v[e]);
                    cs3[e] += f; rsum3 += f;
                }
            }
        }
        #pragma unroll
        for (int m = 1; m < 16; m <<= 1) {
            rsum2 += __shfl_xor(rsum2, m);
            rsum3 += __shfl_xor(rsum3, m);
        }
        if (jj == 0) {
            RSvT[((size_t)b * 64 + g16) * PP + p]      = rsum2;  // ch 64+g16
            RSvT[((size_t)b * 64 + 32 + g16) * PP + p] = rsum3;  // ch 96+g16
        }
        __syncthreads();                     // (D) v_l reads done before next GEMM1
    }
    // strip-partial col sums -> CSp (jc: ch32+g16 -> g16 ; ch96+g16 -> 32+g16)
    {
        float* dst = CSp + ((size_t)(b * KSTRIP + strip)) * 64 * PP;
        f32x4 a = {cs1[0], cs1[1], cs1[2], cs1[3]};
        f32x4 c = {cs1[4], cs1[5], cs1[6], cs1[7]};
        *(f32x4*)(dst + (size_t)g16 * PP + jj * 8)     = a;
        *(f32x4*)(dst + (size_t)g16 * PP + jj * 8 + 4) = c;
        f32x4 d = {cs3[0], cs3[1], cs3[2], cs3[3]};
        f32x4 e = {cs3[4], cs3[5], cs3[6], cs3[7]};
        *(f32x4*)(dst + (size_t)(32 + g16) * PP + jj * 8)     = d;
        *(f32x4*)(dst + (size_t)(32 + g16) * PP + jj * 8 + 4) = e;
    }
}

// ---------------------------------------------------------------------------
// K2s: CSv[b][jc][q] = sum over 16 strips of CSp.  Grid 32 b x 8 groups.
// ---------------------------------------------------------------------------
__global__ __launch_bounds__(256) void k2s_reduce(const float* __restrict__ CSp,
        float* __restrict__ CSv) {
    int bx = blockIdx.x;
    int b = bx >> 3, grp = bx & 7;
    int tid = threadIdx.x;
    #pragma unroll
    for (int it = 0; it < 4; ++it) {
        int jc = grp * 8 + it * 2 + (tid >> 7);
        int q = tid & 127;
        float s = 0.f;
        #pragma unroll
        for (int st = 0; st < KSTRIP; ++st)
            s += CSp[(((size_t)(b * KSTRIP + st)) * 64 + jc) * PP + q];
        CSv[((size_t)b * 64 + jc) * PP + q] = s;
    }
}

// ---------------------------------------------------------------------------
// K3: pure streaming postprocess.  One block per (b,ch); reads the v2 plane
// once, applies the affine closed form from RSvT/CSv (g3 total = sum of cs).
// ---------------------------------------------------------------------------
__global__ __launch_bounds__(256) void k3_out(const unsigned short* __restrict__ v2,
        const float* __restrict__ RSvT, const float* __restrict__ CSv,
        float* __restrict__ out) {
    int bx = blockIdx.x;
    int b = bx >> 7, ch = bx & 127;
    int g = ch >> 5;
    __shared__ float rs_l[128], cs_l[128];
    __shared__ float part[4];
    int tid = threadIdx.x;
    size_t base = (size_t)(b * NCH + ch) * (PP * PP);
    const unsigned short* src = v2 + base;
    float* dst = out + base;
    if (tid < 128) {
        if (g >= 2) rs_l[tid] = RSvT[((size_t)b * 64 + (ch - 64)) * PP + tid];
        if (g == 1) cs_l[tid] = CSv[((size_t)b * 64 + (ch - 32)) * PP + tid];
        if (g == 3) cs_l[tid] = CSv[((size_t)b * 64 + 32 + (ch - 96)) * PP + tid];
    }
    __syncthreads();
    float stot = 0.f;
    if (g == 3) {
        float s = (tid < 128) ? cs_l[tid] : 0.f;
        #pragma unroll
        for (int m = 1; m < 64; m <<= 1) s += __shfl_xor(s, m);
        if ((tid & 63) == 0) part[tid >> 6] = s;
        __syncthreads();
        stot = part[0] + part[1];
    }
    #pragma unroll
    for (int i = 0; i < 8; ++i) {
        int k = tid + i * 256;
        int pr = k >> 4, q0 = (k & 15) * 8;
        bf16x8 u = *(const bf16x8*)(src + pr * PP + q0);
        float rp = (g >= 2) ? rs_l[pr] : 0.f;
        float o8[8];
        #pragma unroll
        for (int e = 0; e < 8; ++e) {
            float v = bf2f((unsigned short)u[e]);
            float cq = cs_l[q0 + e];
            float r;
            if (g == 0)      r = v;
            else if (g == 1) r = (cq - v) * (1.f / 3.f);
            else if (g == 2) r = (rp - v) * (1.f / 3.f);
            else             r = ((stot - rp) - cq + v) * (1.f / 9.f);
            o8[e] = r;
        }
        f32x4 lo = {o8[0], o8[1], o8[2], o8[3]};
        f32x4 hi = {o8[4], o8[5], o8[6], o8[7]};
        *(f32x4*)(dst + pr * PP + q0)     = lo;
        *(f32x4*)(dst + pr * PP + q0 + 4) = hi;
    }
}

// ---------------------------------------------------------------------------
extern "C" void kernel_launch(void* const* d_in, const int* in_sizes, int n_in,
                              void* d_out, int out_size, void* d_ws, size_t ws_size,
                              hipStream_t stream) {
    (void)in_sizes; (void)n_in; (void)out_size; (void)ws_size;
    const float* phi = (const float*)d_in[0];
    const float* W1  = (const float*)d_in[1];
    const float* b1  = (const float*)d_in[2];
    const float* W3  = (const float*)d_in[3];
    const float* b3  = (const float*)d_in[4];
    float* out = (float*)d_out;

    char* ws = (char*)d_ws;
    size_t off = 0;
    unsigned short* v2 = (unsigned short*)(ws + off); off += (size_t)BATCH * NCH * PP * PP * 2; // 134 MB
    float* RS1t = (float*)(ws + off); off += (size_t)BATCH * NCH * PP * 4;            // 2 MB
    float* CS1p = (float*)(ws + off); off += (size_t)BATCH * NSTRIP * NCH * PP * 4;   // 16 MB
    float* Ap   = (float*)(ws + off); off += (size_t)BATCH * NCH * PP * 4;            // 8 MB
    float* Bqt  = (float*)(ws + off); off += (size_t)BATCH * NCH * PP * 4;            // 8 MB
    unsigned short* W3bf = (unsigned short*)(ws + off); off += (size_t)NCH * NCH * 2; // 32 KB
    float* RSvT = (float*)(ws + off); off += (size_t)BATCH * 64 * PP * 4;             // 1 MB
    float* CSp  = (float*)(ws + off); off += (size_t)BATCH * KSTRIP * 64 * PP * 4;    // 16.8 MB
    float* CSv  = (float*)(ws + off); off += (size_t)BATCH * 64 * PP * 4;             // 1 MB

    k1_sums<<<BATCH * NSTRIP, 512, 0, stream>>>(phi, W1, b1, RS1t, CS1p);
    k1b_planes<<<BATCH * 4, 256, 0, stream>>>(W3, b3, RS1t, CS1p, Ap, Bqt, W3bf);
    k2_mfma<<<BATCH * KSTRIP, 512, 0, stream>>>(phi, W1, b1, W3bf, Ap, Bqt, v2, RSvT, CSp);
    k2s_reduce<<<BATCH * 8, 256, 0, stream>>>(CSp, CSv);
    k3_out<<<BATCH * NCH, 256, 0, stream>>>(v2, RSvT, CSv, out);
}

// Round 13
// 195.054 us; speedup vs baseline: 1.1839x; 1.1355x over previous
//
#include <hip/hip_runtime.h>
#include <stdint.h>

#define BATCH 32
#define CIN   8
#define NCH   128   // 4*F_DIM
#define PP    128   // P
#define NSTRIP 8    // k1 strips per batch (16 p each)
#define KSTRIP 16   // k2 strips per batch (8 p each)

typedef __attribute__((ext_vector_type(8))) short    bf16x8;
typedef __attribute__((ext_vector_type(4))) float    f32x4;

__device__ __forceinline__ float bf2f(unsigned short u) {
    union { unsigned int i; float f; } x; x.i = ((unsigned int)u) << 16; return x.f;
}
__device__ __forceinline__ unsigned short f2bf(float f) {
    union { float f; unsigned int i; } x; x.f = f;
    unsigned int r = x.i + 0x7fffu + ((x.i >> 16) & 1u);
    return (unsigned short)(r >> 16);
}
__device__ __forceinline__ unsigned int pk2(float a, float b) {
    return (unsigned int)f2bf(a) | ((unsigned int)f2bf(b) << 16);
}

// Swizzled byte offset into a [128 rows][128 bf16] LDS tile (row = 256 B).
#define SWZB(row, cb) (((row) << 8) + ((cb) ^ (((row) & 7) << 4)))

// ---------------------------------------------------------------------------
// K1 (MFMA): RS1t[b][p][c] = sum_q t ; CS1p[b][strip][c][q] partial (R10).
// ---------------------------------------------------------------------------
__global__ __launch_bounds__(512, 4) void k1_sums(const float* __restrict__ phi,
        const float* __restrict__ W1, const float* __restrict__ b1,
        float* __restrict__ RS1t, float* __restrict__ CS1p) {
    __shared__ float cs_f[128 * 132];           // 67.6 KB, live only at flush
    __shared__ unsigned short phi_b[2][1024];   // [q][ci] bf16
    int bx = blockIdx.x;
    int b = bx >> 3, strip = bx & 7;
    int p0 = strip * 16;
    int tid = threadIdx.x;
    int wv = tid >> 6, l = tid & 63, lr = l & 15, lg = l >> 4;
    int c0 = wv * 16 + lg * 4;

    bf16x8 w1fr = {0, 0, 0, 0, 0, 0, 0, 0};
    if (lg == 0) {
        int cc = wv * 16 + lr;
        float4 wa = *(const float4*)(W1 + cc * 8);
        float4 wb = *(const float4*)(W1 + cc * 8 + 4);
        w1fr[0] = (short)f2bf(wa.x); w1fr[1] = (short)f2bf(wa.y);
        w1fr[2] = (short)f2bf(wa.z); w1fr[3] = (short)f2bf(wa.w);
        w1fr[4] = (short)f2bf(wb.x); w1fr[5] = (short)f2bf(wb.y);
        w1fr[6] = (short)f2bf(wb.z); w1fr[7] = (short)f2bf(wb.w);
    }
    f32x4 binit = {b1[c0], b1[c0 + 1], b1[c0 + 2], b1[c0 + 3]};
    if (tid < 128) {
        bf16x8 pv;
        #pragma unroll
        for (int ci = 0; ci < 8; ++ci)
            pv[ci] = (short)f2bf(phi[((size_t)(b * CIN + ci) * PP + p0) * PP + tid]);
        *(bf16x8*)(phi_b[0] + tid * 8) = pv;
    }
    __syncthreads();

    f32x4 cs_acc[8];
    #pragma unroll
    for (int i = 0; i < 8; ++i) { f32x4 z = {0.f, 0.f, 0.f, 0.f}; cs_acc[i] = z; }

    int cur = 0;
    for (int r = 0; r < 16; ++r) {
        int p = p0 + r;
        float pfv[8];
        if (r < 15 && tid < 128) {
            #pragma unroll
            for (int ci = 0; ci < 8; ++ci)
                pfv[ci] = phi[((size_t)(b * CIN + ci) * PP + p + 1) * PP + tid];
        }
        const unsigned short* pb = phi_b[cur];
        f32x4 rs4 = {0.f, 0.f, 0.f, 0.f};
        #pragma unroll
        for (int pt = 0; pt < 8; ++pt) {
            int pix = pt * 16 + lr;
            bf16x8 bfr1 = {0, 0, 0, 0, 0, 0, 0, 0};
            if (lg == 0) bfr1 = *(const bf16x8*)(pb + pix * 8);
            f32x4 a = __builtin_amdgcn_mfma_f32_16x16x32_bf16(w1fr, bfr1, binit, 0, 0, 0);
            f32x4 v = {fmaxf(a.x, 0.f), fmaxf(a.y, 0.f), fmaxf(a.z, 0.f), fmaxf(a.w, 0.f)};
            cs_acc[pt] += v;
            rs4 += v;
        }
        #pragma unroll
        for (int m = 1; m < 16; m <<= 1) {
            rs4.x += __shfl_xor(rs4.x, m);
            rs4.y += __shfl_xor(rs4.y, m);
            rs4.z += __shfl_xor(rs4.z, m);
            rs4.w += __shfl_xor(rs4.w, m);
        }
        if (lr == 0)
            *(f32x4*)(RS1t + ((size_t)b * PP + p) * NCH + c0) = rs4;
        if (r < 15 && tid < 128) {
            bf16x8 pv;
            #pragma unroll
            for (int ci = 0; ci < 8; ++ci) pv[ci] = (short)f2bf(pfv[ci]);
            *(bf16x8*)(phi_b[cur ^ 1] + tid * 8) = pv;
        }
        __syncthreads();
        cur ^= 1;
    }
    #pragma unroll
    for (int pt = 0; pt < 8; ++pt) {
        f32x4 v = cs_acc[pt];
        int q = pt * 16 + lr;
        cs_f[(c0 + 0) * 132 + q] = v.x;
        cs_f[(c0 + 1) * 132 + q] = v.y;
        cs_f[(c0 + 2) * 132 + q] = v.z;
        cs_f[(c0 + 3) * 132 + q] = v.w;
    }
    __syncthreads();
    float* dstp = CS1p + (size_t)(b * NSTRIP + strip) * NCH * PP;
    for (int k = tid; k < 16384; k += 512) {
        int cc = k >> 7, q = k & 127;
        dstp[k] = cs_f[cc * 132 + q];
    }
}

// ---------------------------------------------------------------------------
// K1b: Ap[b][o][q], Bqt[b][p][o] (with Cc folded in), W3bf (block 0).
// ---------------------------------------------------------------------------
__global__ __launch_bounds__(256) void k1b_planes(const float* __restrict__ W3,
        const float* __restrict__ b3, const float* __restrict__ RS1t,
        const float* __restrict__ CS1p, float* __restrict__ Ap,
        float* __restrict__ Bqt, unsigned short* __restrict__ W3bf) {
    int bx = blockIdx.x;
    int b = bx >> 2, og = bx & 3;
    int tid = threadIdx.x;
    __shared__ float cs_g[64][132];
    __shared__ float rs_g[64][132];
    __shared__ float s1_96[32];
    for (int k = tid; k < 64 * 128; k += 256) {
        int r = k >> 7, q = k & 127;
        int ch_c = (r < 32) ? (32 + r) : (64 + r);
        float s = 0.f;
        #pragma unroll
        for (int s8 = 0; s8 < NSTRIP; ++s8)
            s += CS1p[((size_t)(b * NSTRIP + s8) * NCH + ch_c) * PP + q];
        cs_g[r][q] = s;
    }
    for (int k = tid; k < 64 * 128; k += 256) {
        int p = k >> 6, r = k & 63;
        rs_g[r][p] = RS1t[((size_t)b * PP + p) * NCH + 64 + r];
    }
    __syncthreads();
    if (tid < 32) {
        float s = 0.f;
        for (int q = 0; q < 128; ++q) s += cs_g[32 + tid][q];
        s1_96[tid] = s;
    }
    int o = og * 32 + (tid >> 3), qh = tid & 7;
    {
        float wa[64];
        #pragma unroll
        for (int r = 0; r < 64; ++r)
            wa[r] = (r < 32) ? W3[o * NCH + 32 + r] * (1.f / 3.f)
                             : -W3[o * NCH + 64 + r] * (1.f / 9.f);
        #pragma unroll
        for (int j = 0; j < 4; ++j) {
            int q = qh * 16 + j * 4;
            float4 a = {0.f, 0.f, 0.f, 0.f};
            #pragma unroll
            for (int r = 0; r < 64; ++r) {
                float4 cv = *(const float4*)&cs_g[r][q];
                a.x = fmaf(wa[r], cv.x, a.x);
                a.y = fmaf(wa[r], cv.y, a.y);
                a.z = fmaf(wa[r], cv.z, a.z);
                a.w = fmaf(wa[r], cv.w, a.w);
            }
            *(float4*)&Ap[((size_t)b * NCH + o) * PP + q] = a;
        }
    }
    __syncthreads();
    float cc = b3[o];
    #pragma unroll
    for (int r = 0; r < 32; ++r)
        cc = fmaf(W3[o * NCH + 96 + r] * (1.f / 9.f), s1_96[r], cc);
    {
        float wb[64];
        #pragma unroll
        for (int r = 0; r < 64; ++r)
            wb[r] = (r < 32) ? W3[o * NCH + 64 + r] * (1.f / 3.f)
                             : -W3[o * NCH + 64 + r] * (1.f / 9.f);
        #pragma unroll
        for (int j = 0; j < 4; ++j) {
            int p4 = qh * 16 + j * 4;
            float4 a = {0.f, 0.f, 0.f, 0.f};
            #pragma unroll
            for (int r = 0; r < 64; ++r) {
                float4 rv = *(const float4*)&rs_g[r][p4];
                a.x = fmaf(wb[r], rv.x, a.x);
                a.y = fmaf(wb[r], rv.y, a.y);
                a.z = fmaf(wb[r], rv.z, a.z);
                a.w = fmaf(wb[r], rv.w, a.w);
            }
            Bqt[((size_t)b * PP + p4 + 0) * NCH + o] = a.x + cc;
            Bqt[((size_t)b * PP + p4 + 1) * NCH + o] = a.y + cc;
            Bqt[((size_t)b * PP + p4 + 2) * NCH + o] = a.z + cc;
            Bqt[((size_t)b * PP + p4 + 3) * NCH + o] = a.w + cc;
        }
    }
    if (bx == 0) {
        for (int i = 0; i < 16; ++i) {
            int k = tid + i * 256;
            float4 w = *(const float4*)(W3 + k * 4);
            int c0 = (k * 4) & 127;
            float sc = (c0 < 32) ? 1.f : ((c0 < 96) ? (-1.f / 3.f) : (1.f / 9.f));
            unsigned int lo = pk2(w.x * sc, w.y * sc);
            unsigned int hi = pk2(w.z * sc, w.w * sc);
            uint2 u = {lo, hi};
            *(uint2*)(W3bf + k * 4) = u;
        }
    }
}

// ---------------------------------------------------------------------------
// K2: SLIM MFMA kernel (byte-identical to R10 — spill-free, Ap hoisted).
// ---------------------------------------------------------------------------
__global__ __launch_bounds__(512, 4) void k2_mfma(const float* __restrict__ phi,
        const float* __restrict__ W1, const float* __restrict__ b1,
        const unsigned short* __restrict__ W3bf,
        const float* __restrict__ Ap, const float* __restrict__ Bqt,
        unsigned short* __restrict__ v2) {
    int bx = blockIdx.x;
    int b = bx >> 4, strip = bx & 15;
    int p0 = strip * 8;
    __shared__ unsigned short w3_l[16384];
    __shared__ unsigned short t_l[16384];
    __shared__ unsigned short phi_b[2][1024];
    __shared__ float BC_l[2][128];
    int tid = threadIdx.x;
    int wv = tid >> 6, l = tid & 63, lr = l & 15, lg = l >> 4;
    int q0 = wv * 16 + lg * 4;

    #pragma unroll
    for (int i = 0; i < 4; ++i) {
        int k = tid + i * 512;
        int o = k >> 4, cb = (k & 15) * 16;
        bf16x8 v = *(const bf16x8*)(W3bf + k * 8);
        *(bf16x8*)((char*)w3_l + SWZB(o, cb)) = v;
    }
    bf16x8 w1fr = {0, 0, 0, 0, 0, 0, 0, 0};
    if (lg == 0) {
        int cc = wv * 16 + lr;
        float4 wa = *(const float4*)(W1 + cc * 8);
        float4 wb = *(const float4*)(W1 + cc * 8 + 4);
        w1fr[0] = (short)f2bf(wa.x); w1fr[1] = (short)f2bf(wa.y);
        w1fr[2] = (short)f2bf(wa.z); w1fr[3] = (short)f2bf(wa.w);
        w1fr[4] = (short)f2bf(wb.x); w1fr[5] = (short)f2bf(wb.y);
        w1fr[6] = (short)f2bf(wb.z); w1fr[7] = (short)f2bf(wb.w);
    }
    int c0 = wv * 16 + lg * 4;
    f32x4 binit = {b1[c0], b1[c0 + 1], b1[c0 + 2], b1[c0 + 3]};
    f32x4 apr[8];
    #pragma unroll
    for (int nt = 0; nt < 8; ++nt)
        apr[nt] = *(const f32x4*)(Ap + ((size_t)(b * NCH + nt * 16 + lr)) * PP + q0);
    if (tid < 128) {
        bf16x8 pv;
        #pragma unroll
        for (int ci = 0; ci < 8; ++ci)
            pv[ci] = (short)f2bf(phi[((size_t)(b * CIN + ci) * PP + p0) * PP + tid]);
        *(bf16x8*)(phi_b[0] + tid * 8) = pv;
        BC_l[0][tid] = Bqt[((size_t)b * PP + p0) * NCH + tid];
    }
    __syncthreads();

    for (int r = 0; r < 8; ++r) {
        int cur = r & 1, nxt = cur ^ 1;
        int p = p0 + r;
        float pfv[8]; float bcn = 0.f;
        if (r < 7 && tid < 128) {
            #pragma unroll
            for (int ci = 0; ci < 8; ++ci)
                pfv[ci] = phi[((size_t)(b * CIN + ci) * PP + p + 1) * PP + tid];
            bcn = Bqt[((size_t)b * PP + p + 1) * NCH + tid];
        }
        const unsigned short* pb = phi_b[cur];
        #pragma unroll
        for (int pt = 0; pt < 8; ++pt) {
            int pix = pt * 16 + lr;
            bf16x8 bfr1 = {0, 0, 0, 0, 0, 0, 0, 0};
            if (lg == 0) bfr1 = *(const bf16x8*)(pb + pix * 8);
            f32x4 a = __builtin_amdgcn_mfma_f32_16x16x32_bf16(w1fr, bfr1, binit, 0, 0, 0);
            uint2 u;
            u.x = pk2(fmaxf(a.x, 0.f), fmaxf(a.y, 0.f));
            u.y = pk2(fmaxf(a.z, 0.f), fmaxf(a.w, 0.f));
            *(uint2*)((char*)t_l + SWZB(pix, c0 * 2)) = u;
        }
        __syncthreads();                     // (A) t_l ready
        bf16x8 afr[4];
        #pragma unroll
        for (int ks = 0; ks < 4; ++ks)
            afr[ks] = *(const bf16x8*)((char*)t_l + SWZB(wv * 16 + lr, ks * 64 + lg * 16));
        __syncthreads();                     // (B) afr reads done -> t_l reusable
        #pragma unroll
        for (int nt = 0; nt < 8; ++nt) {
            int o = nt * 16 + lr;
            bf16x8 bfr[4];
            #pragma unroll
            for (int ks = 0; ks < 4; ++ks)
                bfr[ks] = *(const bf16x8*)((char*)w3_l + SWZB(o, ks * 64 + lg * 16));
            f32x4 acc = apr[nt] + BC_l[cur][o];
            #pragma unroll
            for (int ks = 0; ks < 4; ++ks)
                acc = __builtin_amdgcn_mfma_f32_16x16x32_bf16(afr[ks], bfr[ks], acc, 0, 0, 0);
            uint2 u;
            u.x = pk2(fmaxf(acc.x, 0.f), fmaxf(acc.y, 0.f));
            u.y = pk2(fmaxf(acc.z, 0.f), fmaxf(acc.w, 0.f));
            *(uint2*)((char*)t_l + SWZB(o, q0 * 2)) = u;
        }
        if (r < 7 && tid < 128) {
            bf16x8 pv;
            #pragma unroll
            for (int ci = 0; ci < 8; ++ci) pv[ci] = (short)f2bf(pfv[ci]);
            *(bf16x8*)(phi_b[nxt] + tid * 8) = pv;
            BC_l[nxt][tid] = bcn;
        }
        __syncthreads();                     // (C) v_l complete + next phi ready
        #pragma unroll
        for (int i = 0; i < 4; ++i) {
            int k = tid + i * 512;
            int o = k >> 4, j = k & 15;
            bf16x8 v = *(const bf16x8*)((char*)t_l + SWZB(o, j * 16));
            *(bf16x8*)(v2 + ((size_t)(b * NCH + o) * PP + p) * PP + j * 8) = v;
        }
        __syncthreads();                     // (D) v_l reads done before next GEMM1
    }
}

// ---------------------------------------------------------------------------
// K3: one-pass LDS plane (R10 structure) with IN-STAGING register sums:
// thread (pc=tid>>4, qc=tid&15) owns rows pc+16i and col-slice qc*8..qc*8+7
// -> cs8[8] register col-partials + per-row partial row-sums (rsp LDS).
// No scalar column loop.  LDS ~53 KB -> 3 blocks/CU.
// ---------------------------------------------------------------------------
__global__ __launch_bounds__(256) void k3_out(const unsigned short* __restrict__ v2,
        float* __restrict__ out) {
    int bx = blockIdx.x;
    int b = bx >> 7, ch = bx & 127;
    int g = ch >> 5;
    __shared__ unsigned short v_l[128 * 136];   // 34.8 KB
    __shared__ float rsp[128][17];              // 8.7 KB
    __shared__ float csp[16][132];              // 8.4 KB
    __shared__ float rs_l[128], cs_l[128];
    __shared__ float s_sh;
    int tid = threadIdx.x;
    size_t base = (size_t)(b * NCH + ch) * (PP * PP);
    const unsigned short* src = v2 + base;

    int pc = tid >> 4, qc = tid & 15;
    float cs8[8];
    #pragma unroll
    for (int e = 0; e < 8; ++e) cs8[e] = 0.f;
    #pragma unroll
    for (int i = 0; i < 8; ++i) {
        int k = tid + i * 256;
        int pr = k >> 4;                 // = pc + i*16
        bf16x8 u = *(const bf16x8*)(src + pr * PP + qc * 8);
        *(bf16x8*)(v_l + pr * 136 + qc * 8) = u;
        float rp = 0.f;
        #pragma unroll
        for (int e = 0; e < 8; ++e) {
            float v = bf2f((unsigned short)u[e]);
            cs8[e] += v;
            rp += v;
        }
        rsp[pr][qc] = rp;
    }
    f32x4 clo = {cs8[0], cs8[1], cs8[2], cs8[3]};
    f32x4 chi = {cs8[4], cs8[5], cs8[6], cs8[7]};
    *(f32x4*)&csp[pc][qc * 8]     = clo;
    *(f32x4*)&csp[pc][qc * 8 + 4] = chi;
    __syncthreads();
    if (tid < 128) {
        f32x4 a  = *(const f32x4*)&rsp[tid][0];
        f32x4 c2 = *(const f32x4*)&rsp[tid][4];
        f32x4 c3 = *(const f32x4*)&rsp[tid][8];
        f32x4 c4 = *(const f32x4*)&rsp[tid][12];
        rs_l[tid] = (a.x + a.y + a.z + a.w) + (c2.x + c2.y + c2.z + c2.w)
                  + (c3.x + c3.y + c3.z + c3.w) + (c4.x + c4.y + c4.z + c4.w);
    } else {
        int q = tid - 128;
        float s = 0.f;
        #pragma unroll
        for (int i = 0; i < 16; ++i) s += csp[i][q];
        cs_l[q] = s;
    }
    __syncthreads();
    if (tid < 64) {
        float s = rs_l[tid] + rs_l[tid + 64];
        #pragma unroll
        for (int off = 32; off > 0; off >>= 1) s += __shfl_down(s, off);
        if (tid == 0) s_sh = s;
    }
    __syncthreads();
    float stot = s_sh;
    float* dst = out + base;
    #pragma unroll
    for (int i = 0; i < 8; ++i) {
        int k = tid + i * 256;
        int pr = k >> 4, q0 = (k & 15) * 8;
        bf16x8 u = *(const bf16x8*)(v_l + pr * 136 + q0);
        float rp = rs_l[pr];
        float o8[8];
        #pragma unroll
        for (int e = 0; e < 8; ++e) {
            float v = bf2f((unsigned short)u[e]);
            float cq = cs_l[q0 + e];
            float r;
            if (g == 0)      r = v;
            else if (g == 1) r = (cq - v) * (1.f / 3.f);
            else if (g == 2) r = (rp - v) * (1.f / 3.f);
            else             r = ((stot - rp) - cq + v) * (1.f / 9.f);
            o8[e] = r;
        }
        f32x4 lo = {o8[0], o8[1], o8[2], o8[3]};
        f32x4 hi = {o8[4], o8[5], o8[6], o8[7]};
        *(f32x4*)(dst + pr * PP + q0)     = lo;
        *(f32x4*)(dst + pr * PP + q0 + 4) = hi;
    }
}

// ---------------------------------------------------------------------------
extern "C" void kernel_launch(void* const* d_in, const int* in_sizes, int n_in,
                              void* d_out, int out_size, void* d_ws, size_t ws_size,
                              hipStream_t stream) {
    (void)in_sizes; (void)n_in; (void)out_size; (void)ws_size;
    const float* phi = (const float*)d_in[0];
    const float* W1  = (const float*)d_in[1];
    const float* b1  = (const float*)d_in[2];
    const float* W3  = (const float*)d_in[3];
    const float* b3  = (const float*)d_in[4];
    float* out = (float*)d_out;

    char* ws = (char*)d_ws;
    size_t off = 0;
    unsigned short* v2 = (unsigned short*)(ws + off); off += (size_t)BATCH * NCH * PP * PP * 2; // 134 MB
    float* RS1t = (float*)(ws + off); off += (size_t)BATCH * NCH * PP * 4;            // 2 MB
    float* CS1p = (float*)(ws + off); off += (size_t)BATCH * NSTRIP * NCH * PP * 4;   // 16 MB
    float* Ap   = (float*)(ws + off); off += (size_t)BATCH * NCH * PP * 4;            // 8 MB
    float* Bqt  = (float*)(ws + off); off += (size_t)BATCH * NCH * PP * 4;            // 8 MB
    unsigned short* W3bf = (unsigned short*)(ws + off); off += (size_t)NCH * NCH * 2; // 32 KB

    k1_sums<<<BATCH * NSTRIP, 512, 0, stream>>>(phi, W1, b1, RS1t, CS1p);
    k1b_planes<<<BATCH * 4, 256, 0, stream>>>(W3, b3, RS1t, CS1p, Ap, Bqt, W3bf);
    k2_mfma<<<BATCH * KSTRIP, 512, 0, stream>>>(phi, W1, b1, W3bf, Ap, Bqt, v2);
    k3_out<<<BATCH * NCH, 256, 0, stream>>>(v2, out);
}

// Round 14
// 191.887 us; speedup vs baseline: 1.2034x; 1.0165x over previous
//
#include <hip/hip_runtime.h>
#include <stdint.h>

#define BATCH 32
#define CIN   8
#define NCH   128   // 4*F_DIM
#define PP    128   // P
#define NSTRIP 8    // k1 strips per batch (16 p each)
#define KSTRIP 16   // k2 strips per batch (8 p each)

typedef __attribute__((ext_vector_type(8))) short    bf16x8;
typedef __attribute__((ext_vector_type(4))) float    f32x4;

__device__ __forceinline__ float bf2f(unsigned short u) {
    union { unsigned int i; float f; } x; x.i = ((unsigned int)u) << 16; return x.f;
}
__device__ __forceinline__ unsigned short f2bf(float f) {
    union { float f; unsigned int i; } x; x.f = f;
    unsigned int r = x.i + 0x7fffu + ((x.i >> 16) & 1u);
    return (unsigned short)(r >> 16);
}
__device__ __forceinline__ unsigned int pk2(float a, float b) {
    return (unsigned int)f2bf(a) | ((unsigned int)f2bf(b) << 16);
}

// Swizzled byte offset into a [128 rows][128 bf16] LDS tile (row = 256 B).
#define SWZB(row, cb) (((row) << 8) + ((cb) ^ (((row) & 7) << 4)))

// ---------------------------------------------------------------------------
// K1 (MFMA): RS1t[b][p][c] = sum_q t ; CS1p[b][strip][c][q] partial (R10).
// ---------------------------------------------------------------------------
__global__ __launch_bounds__(512, 4) void k1_sums(const float* __restrict__ phi,
        const float* __restrict__ W1, const float* __restrict__ b1,
        float* __restrict__ RS1t, float* __restrict__ CS1p) {
    __shared__ float cs_f[128 * 132];
    __shared__ unsigned short phi_b[2][1024];
    int bx = blockIdx.x;
    int b = bx >> 3, strip = bx & 7;
    int p0 = strip * 16;
    int tid = threadIdx.x;
    int wv = tid >> 6, l = tid & 63, lr = l & 15, lg = l >> 4;
    int c0 = wv * 16 + lg * 4;

    bf16x8 w1fr = {0, 0, 0, 0, 0, 0, 0, 0};
    if (lg == 0) {
        int cc = wv * 16 + lr;
        float4 wa = *(const float4*)(W1 + cc * 8);
        float4 wb = *(const float4*)(W1 + cc * 8 + 4);
        w1fr[0] = (short)f2bf(wa.x); w1fr[1] = (short)f2bf(wa.y);
        w1fr[2] = (short)f2bf(wa.z); w1fr[3] = (short)f2bf(wa.w);
        w1fr[4] = (short)f2bf(wb.x); w1fr[5] = (short)f2bf(wb.y);
        w1fr[6] = (short)f2bf(wb.z); w1fr[7] = (short)f2bf(wb.w);
    }
    f32x4 binit = {b1[c0], b1[c0 + 1], b1[c0 + 2], b1[c0 + 3]};
    if (tid < 128) {
        bf16x8 pv;
        #pragma unroll
        for (int ci = 0; ci < 8; ++ci)
            pv[ci] = (short)f2bf(phi[((size_t)(b * CIN + ci) * PP + p0) * PP + tid]);
        *(bf16x8*)(phi_b[0] + tid * 8) = pv;
    }
    __syncthreads();

    f32x4 cs_acc[8];
    #pragma unroll
    for (int i = 0; i < 8; ++i) { f32x4 z = {0.f, 0.f, 0.f, 0.f}; cs_acc[i] = z; }

    int cur = 0;
    for (int r = 0; r < 16; ++r) {
        int p = p0 + r;
        float pfv[8];
        if (r < 15 && tid < 128) {
            #pragma unroll
            for (int ci = 0; ci < 8; ++ci)
                pfv[ci] = phi[((size_t)(b * CIN + ci) * PP + p + 1) * PP + tid];
        }
        const unsigned short* pb = phi_b[cur];
        f32x4 rs4 = {0.f, 0.f, 0.f, 0.f};
        #pragma unroll
        for (int pt = 0; pt < 8; ++pt) {
            int pix = pt * 16 + lr;
            bf16x8 bfr1 = {0, 0, 0, 0, 0, 0, 0, 0};
            if (lg == 0) bfr1 = *(const bf16x8*)(pb + pix * 8);
            f32x4 a = __builtin_amdgcn_mfma_f32_16x16x32_bf16(w1fr, bfr1, binit, 0, 0, 0);
            f32x4 v = {fmaxf(a.x, 0.f), fmaxf(a.y, 0.f), fmaxf(a.z, 0.f), fmaxf(a.w, 0.f)};
            cs_acc[pt] += v;
            rs4 += v;
        }
        #pragma unroll
        for (int m = 1; m < 16; m <<= 1) {
            rs4.x += __shfl_xor(rs4.x, m);
            rs4.y += __shfl_xor(rs4.y, m);
            rs4.z += __shfl_xor(rs4.z, m);
            rs4.w += __shfl_xor(rs4.w, m);
        }
        if (lr == 0)
            *(f32x4*)(RS1t + ((size_t)b * PP + p) * NCH + c0) = rs4;
        if (r < 15 && tid < 128) {
            bf16x8 pv;
            #pragma unroll
            for (int ci = 0; ci < 8; ++ci) pv[ci] = (short)f2bf(pfv[ci]);
            *(bf16x8*)(phi_b[cur ^ 1] + tid * 8) = pv;
        }
        __syncthreads();
        cur ^= 1;
    }
    #pragma unroll
    for (int pt = 0; pt < 8; ++pt) {
        f32x4 v = cs_acc[pt];
        int q = pt * 16 + lr;
        cs_f[(c0 + 0) * 132 + q] = v.x;
        cs_f[(c0 + 1) * 132 + q] = v.y;
        cs_f[(c0 + 2) * 132 + q] = v.z;
        cs_f[(c0 + 3) * 132 + q] = v.w;
    }
    __syncthreads();
    float* dstp = CS1p + (size_t)(b * NSTRIP + strip) * NCH * PP;
    for (int k = tid; k < 16384; k += 512) {
        int cc = k >> 7, q = k & 127;
        dstp[k] = cs_f[cc * 132 + q];
    }
}

// ---------------------------------------------------------------------------
// K1b: Ap[b][o][q], Bqt[b][p][o] (with Cc folded in), W3bf (block 0).
// ---------------------------------------------------------------------------
__global__ __launch_bounds__(256) void k1b_planes(const float* __restrict__ W3,
        const float* __restrict__ b3, const float* __restrict__ RS1t,
        const float* __restrict__ CS1p, float* __restrict__ Ap,
        float* __restrict__ Bqt, unsigned short* __restrict__ W3bf) {
    int bx = blockIdx.x;
    int b = bx >> 2, og = bx & 3;
    int tid = threadIdx.x;
    __shared__ float cs_g[64][132];
    __shared__ float rs_g[64][132];
    __shared__ float s1_96[32];
    for (int k = tid; k < 64 * 128; k += 256) {
        int r = k >> 7, q = k & 127;
        int ch_c = (r < 32) ? (32 + r) : (64 + r);
        float s = 0.f;
        #pragma unroll
        for (int s8 = 0; s8 < NSTRIP; ++s8)
            s += CS1p[((size_t)(b * NSTRIP + s8) * NCH + ch_c) * PP + q];
        cs_g[r][q] = s;
    }
    for (int k = tid; k < 64 * 128; k += 256) {
        int p = k >> 6, r = k & 63;
        rs_g[r][p] = RS1t[((size_t)b * PP + p) * NCH + 64 + r];
    }
    __syncthreads();
    if (tid < 32) {
        float s = 0.f;
        for (int q = 0; q < 128; ++q) s += cs_g[32 + tid][q];
        s1_96[tid] = s;
    }
    int o = og * 32 + (tid >> 3), qh = tid & 7;
    {
        float wa[64];
        #pragma unroll
        for (int r = 0; r < 64; ++r)
            wa[r] = (r < 32) ? W3[o * NCH + 32 + r] * (1.f / 3.f)
                             : -W3[o * NCH + 64 + r] * (1.f / 9.f);
        #pragma unroll
        for (int j = 0; j < 4; ++j) {
            int q = qh * 16 + j * 4;
            float4 a = {0.f, 0.f, 0.f, 0.f};
            #pragma unroll
            for (int r = 0; r < 64; ++r) {
                float4 cv = *(const float4*)&cs_g[r][q];
                a.x = fmaf(wa[r], cv.x, a.x);
                a.y = fmaf(wa[r], cv.y, a.y);
                a.z = fmaf(wa[r], cv.z, a.z);
                a.w = fmaf(wa[r], cv.w, a.w);
            }
            *(float4*)&Ap[((size_t)b * NCH + o) * PP + q] = a;
        }
    }
    __syncthreads();
    float cc = b3[o];
    #pragma unroll
    for (int r = 0; r < 32; ++r)
        cc = fmaf(W3[o * NCH + 96 + r] * (1.f / 9.f), s1_96[r], cc);
    {
        float wb[64];
        #pragma unroll
        for (int r = 0; r < 64; ++r)
            wb[r] = (r < 32) ? W3[o * NCH + 64 + r] * (1.f / 3.f)
                             : -W3[o * NCH + 64 + r] * (1.f / 9.f);
        #pragma unroll
        for (int j = 0; j < 4; ++j) {
            int p4 = qh * 16 + j * 4;
            float4 a = {0.f, 0.f, 0.f, 0.f};
            #pragma unroll
            for (int r = 0; r < 64; ++r) {
                float4 rv = *(const float4*)&rs_g[r][p4];
                a.x = fmaf(wb[r], rv.x, a.x);
                a.y = fmaf(wb[r], rv.y, a.y);
                a.z = fmaf(wb[r], rv.z, a.z);
                a.w = fmaf(wb[r], rv.w, a.w);
            }
            Bqt[((size_t)b * PP + p4 + 0) * NCH + o] = a.x + cc;
            Bqt[((size_t)b * PP + p4 + 1) * NCH + o] = a.y + cc;
            Bqt[((size_t)b * PP + p4 + 2) * NCH + o] = a.z + cc;
            Bqt[((size_t)b * PP + p4 + 3) * NCH + o] = a.w + cc;
        }
    }
    if (bx == 0) {
        for (int i = 0; i < 16; ++i) {
            int k = tid + i * 256;
            float4 w = *(const float4*)(W3 + k * 4);
            int c0 = (k * 4) & 127;
            float sc = (c0 < 32) ? 1.f : ((c0 < 96) ? (-1.f / 3.f) : (1.f / 9.f));
            unsigned int lo = pk2(w.x * sc, w.y * sc);
            unsigned int hi = pk2(w.z * sc, w.w * sc);
            uint2 u = {lo, hi};
            *(uint2*)(W3bf + k * 4) = u;
        }
    }
}

// ---------------------------------------------------------------------------
// K2a: v-SUMS pass, NO v materialization.  GEMM2 only nt 2..7 (ch >= 32);
// acc stays in registers: cs partials in 16 VGPR (lane->(o,q) row-invariant),
// row sums via 2x shfl_xor + rs_part LDS.  2 barriers/row.
// RSvT[b][p][jr] (jr = o-64); CSp[b][strip][jc][q] at kernel end.
// ---------------------------------------------------------------------------
__global__ __launch_bounds__(512) void k2a_sums(const float* __restrict__ phi,
        const float* __restrict__ W1, const float* __restrict__ b1,
        const unsigned short* __restrict__ W3bf,
        const float* __restrict__ Ap, const float* __restrict__ Bqt,
        float* __restrict__ RSvT, float* __restrict__ CSp) {
    int bx = blockIdx.x;
    int b = bx >> 4, strip = bx & 15;
    int p0 = strip * 8;
    __shared__ unsigned short w3_l[16384];
    __shared__ unsigned short t_l[16384];
    __shared__ unsigned short phi_b[2][1024];
    __shared__ float BC_l[2][128];
    __shared__ float rs_part[8][64];
    int tid = threadIdx.x;
    int wv = tid >> 6, l = tid & 63, lr = l & 15, lg = l >> 4;
    int q0 = wv * 16 + lg * 4;
    int c0 = q0;

    #pragma unroll
    for (int i = 0; i < 4; ++i) {
        int k = tid + i * 512;
        int o = k >> 4, cb = (k & 15) * 16;
        bf16x8 v = *(const bf16x8*)(W3bf + k * 8);
        *(bf16x8*)((char*)w3_l + SWZB(o, cb)) = v;
    }
    bf16x8 w1fr = {0, 0, 0, 0, 0, 0, 0, 0};
    if (lg == 0) {
        int cc = wv * 16 + lr;
        float4 wa = *(const float4*)(W1 + cc * 8);
        float4 wb = *(const float4*)(W1 + cc * 8 + 4);
        w1fr[0] = (short)f2bf(wa.x); w1fr[1] = (short)f2bf(wa.y);
        w1fr[2] = (short)f2bf(wa.z); w1fr[3] = (short)f2bf(wa.w);
        w1fr[4] = (short)f2bf(wb.x); w1fr[5] = (short)f2bf(wb.y);
        w1fr[6] = (short)f2bf(wb.z); w1fr[7] = (short)f2bf(wb.w);
    }
    f32x4 binit = {b1[c0], b1[c0 + 1], b1[c0 + 2], b1[c0 + 3]};
    f32x4 apr[6];
    #pragma unroll
    for (int nt = 2; nt < 8; ++nt)
        apr[nt - 2] = *(const f32x4*)(Ap + ((size_t)(b * NCH + nt * 16 + lr)) * PP + q0);
    if (tid < 128) {
        bf16x8 pv;
        #pragma unroll
        for (int ci = 0; ci < 8; ++ci)
            pv[ci] = (short)f2bf(phi[((size_t)(b * CIN + ci) * PP + p0) * PP + tid]);
        *(bf16x8*)(phi_b[0] + tid * 8) = pv;
        BC_l[0][tid] = Bqt[((size_t)b * PP + p0) * NCH + tid];
    }
    __syncthreads();

    f32x4 cs1a = {0.f,0.f,0.f,0.f}, cs1b = {0.f,0.f,0.f,0.f};
    f32x4 cs3a = {0.f,0.f,0.f,0.f}, cs3b = {0.f,0.f,0.f,0.f};

    for (int r = 0; r < 8; ++r) {
        int cur = r & 1, nxt = cur ^ 1;
        int p = p0 + r;
        float pfv[8]; float bcn = 0.f;
        if (r < 7 && tid < 128) {
            #pragma unroll
            for (int ci = 0; ci < 8; ++ci)
                pfv[ci] = phi[((size_t)(b * CIN + ci) * PP + p + 1) * PP + tid];
            bcn = Bqt[((size_t)b * PP + p + 1) * NCH + tid];
        }
        const unsigned short* pb = phi_b[cur];
        #pragma unroll
        for (int pt = 0; pt < 8; ++pt) {
            int pix = pt * 16 + lr;
            bf16x8 bfr1 = {0, 0, 0, 0, 0, 0, 0, 0};
            if (lg == 0) bfr1 = *(const bf16x8*)(pb + pix * 8);
            f32x4 a = __builtin_amdgcn_mfma_f32_16x16x32_bf16(w1fr, bfr1, binit, 0, 0, 0);
            uint2 u;
            u.x = pk2(fmaxf(a.x, 0.f), fmaxf(a.y, 0.f));
            u.y = pk2(fmaxf(a.z, 0.f), fmaxf(a.w, 0.f));
            *(uint2*)((char*)t_l + SWZB(pix, c0 * 2)) = u;
        }
        __syncthreads();                     // (A) t_l ready
        bf16x8 afr[4];
        #pragma unroll
        for (int ks = 0; ks < 4; ++ks)
            afr[ks] = *(const bf16x8*)((char*)t_l + SWZB(wv * 16 + lr, ks * 64 + lg * 16));
        #pragma unroll
        for (int nt = 2; nt < 8; ++nt) {
            int o = nt * 16 + lr;
            bf16x8 bfr[4];
            #pragma unroll
            for (int ks = 0; ks < 4; ++ks)
                bfr[ks] = *(const bf16x8*)((char*)w3_l + SWZB(o, ks * 64 + lg * 16));
            f32x4 acc = apr[nt - 2] + BC_l[cur][o];
            #pragma unroll
            for (int ks = 0; ks < 4; ++ks)
                acc = __builtin_amdgcn_mfma_f32_16x16x32_bf16(afr[ks], bfr[ks], acc, 0, 0, 0);
            f32x4 v = {fmaxf(acc.x, 0.f), fmaxf(acc.y, 0.f), fmaxf(acc.z, 0.f), fmaxf(acc.w, 0.f)};
            if (nt == 2) cs1a += v;
            else if (nt == 3) cs1b += v;
            else if (nt == 6) cs3a += v;
            else if (nt == 7) cs3b += v;
            if (nt >= 4) {
                float rsv = v.x + v.y + v.z + v.w;
                rsv += __shfl_xor(rsv, 16);
                rsv += __shfl_xor(rsv, 32);
                if (lg == 0) rs_part[wv][(nt - 4) * 16 + lr] = rsv;
            }
        }
        if (r < 7 && tid < 128) {
            bf16x8 pv;
            #pragma unroll
            for (int ci = 0; ci < 8; ++ci) pv[ci] = (short)f2bf(pfv[ci]);
            *(bf16x8*)(phi_b[nxt] + tid * 8) = pv;
            BC_l[nxt][tid] = bcn;
        }
        __syncthreads();                     // (B) afr reads + rs_part ready
        if (tid < 64) {
            float s = 0.f;
            #pragma unroll
            for (int w8 = 0; w8 < 8; ++w8) s += rs_part[w8][tid];
            RSvT[((size_t)(b * PP + p)) * 64 + tid] = s;
        }
        // rs_part rewritten only after (A) of next row -> no race
    }
    {
        float* dst = CSp + ((size_t)(b * KSTRIP + strip)) * 64 * PP;
        *(f32x4*)(dst + (size_t)(lr)      * PP + q0) = cs1a;   // ch 32+lr
        *(f32x4*)(dst + (size_t)(16 + lr) * PP + q0) = cs1b;   // ch 48+lr
        *(f32x4*)(dst + (size_t)(32 + lr) * PP + q0) = cs3a;   // ch 96+lr
        *(f32x4*)(dst + (size_t)(48 + lr) * PP + q0) = cs3b;   // ch 112+lr
    }
}

// ---------------------------------------------------------------------------
// K2s: CSv[b][jc][q] = sum_strips CSp ; Sb[b][jo] = sum_p RSvT[b][p][32+jo].
// ---------------------------------------------------------------------------
__global__ __launch_bounds__(256) void k2s_reduce(const float* __restrict__ CSp,
        const float* __restrict__ RSvT, float* __restrict__ CSv,
        float* __restrict__ Sb) {
    int b = blockIdx.x, tid = threadIdx.x;
    for (int k = tid; k < 64 * PP; k += 256) {
        float s = 0.f;
        #pragma unroll
        for (int st = 0; st < KSTRIP; ++st)
            s += CSp[((size_t)(b * KSTRIP + st)) * 64 * PP + k];
        CSv[(size_t)b * 64 * PP + k] = s;
    }
    if (tid < 32) {
        float s = 0.f;
        for (int p = 0; p < PP; ++p) s += RSvT[((size_t)(b * PP + p)) * 64 + 32 + tid];
        Sb[b * 32 + tid] = s;
    }
}

// ---------------------------------------------------------------------------
// K2b: OUTPUT pass.  R10 k2 structure; v_l(=t_l) bf16 staging; store loop
// applies the affine postprocess and writes f32 out in 512B-contiguous
// per-channel-row chunks.  cs/stot per thread are row-invariant -> hoisted
// to registers once; rs per row via 64-float LDS prefetch.
// ---------------------------------------------------------------------------
__global__ __launch_bounds__(512) void k2b_out(const float* __restrict__ phi,
        const float* __restrict__ W1, const float* __restrict__ b1,
        const unsigned short* __restrict__ W3bf,
        const float* __restrict__ Ap, const float* __restrict__ Bqt,
        const float* __restrict__ RSvT, const float* __restrict__ CSv,
        const float* __restrict__ Sb, float* __restrict__ out) {
    int bx = blockIdx.x;
    int b = bx >> 4, strip = bx & 15;
    int p0 = strip * 8;
    __shared__ unsigned short w3_l[16384];
    __shared__ unsigned short t_l[16384];
    __shared__ unsigned short phi_b[2][1024];
    __shared__ float BC_l[2][128];
    __shared__ float rs_row[2][64];
    int tid = threadIdx.x;
    int wv = tid >> 6, l = tid & 63, lr = l & 15, lg = l >> 4;
    int q0 = wv * 16 + lg * 4;
    int c0 = q0;

    #pragma unroll
    for (int i = 0; i < 4; ++i) {
        int k = tid + i * 512;
        int o = k >> 4, cb = (k & 15) * 16;
        bf16x8 v = *(const bf16x8*)(W3bf + k * 8);
        *(bf16x8*)((char*)w3_l + SWZB(o, cb)) = v;
    }
    bf16x8 w1fr = {0, 0, 0, 0, 0, 0, 0, 0};
    if (lg == 0) {
        int cc = wv * 16 + lr;
        float4 wa = *(const float4*)(W1 + cc * 8);
        float4 wb = *(const float4*)(W1 + cc * 8 + 4);
        w1fr[0] = (short)f2bf(wa.x); w1fr[1] = (short)f2bf(wa.y);
        w1fr[2] = (short)f2bf(wa.z); w1fr[3] = (short)f2bf(wa.w);
        w1fr[4] = (short)f2bf(wb.x); w1fr[5] = (short)f2bf(wb.y);
        w1fr[6] = (short)f2bf(wb.z); w1fr[7] = (short)f2bf(wb.w);
    }
    f32x4 binit = {b1[c0], b1[c0 + 1], b1[c0 + 2], b1[c0 + 3]};
    f32x4 apr[8];
    #pragma unroll
    for (int nt = 0; nt < 8; ++nt)
        apr[nt] = *(const f32x4*)(Ap + ((size_t)(b * NCH + nt * 16 + lr)) * PP + q0);
    // row-invariant per-thread cs / stot for the store chunks
    f32x4 csr[4][2];
    float sjr[4];
    #pragma unroll
    for (int i = 0; i < 4; ++i) {
        int k = tid + i * 512;
        int o = k >> 4, j = k & 15;
        int g = o >> 5;
        f32x4 z = {0.f, 0.f, 0.f, 0.f};
        csr[i][0] = z; csr[i][1] = z; sjr[i] = 0.f;
        if (g == 1) {
            int jc = o - 32;
            csr[i][0] = *(const f32x4*)(CSv + ((size_t)b * 64 + jc) * PP + j * 8);
            csr[i][1] = *(const f32x4*)(CSv + ((size_t)b * 64 + jc) * PP + j * 8 + 4);
        } else if (g == 3) {
            int jc = 32 + (o - 96);
            csr[i][0] = *(const f32x4*)(CSv + ((size_t)b * 64 + jc) * PP + j * 8);
            csr[i][1] = *(const f32x4*)(CSv + ((size_t)b * 64 + jc) * PP + j * 8 + 4);
            sjr[i] = Sb[b * 32 + (o - 96)];
        }
    }
    if (tid < 128) {
        bf16x8 pv;
        #pragma unroll
        for (int ci = 0; ci < 8; ++ci)
            pv[ci] = (short)f2bf(phi[((size_t)(b * CIN + ci) * PP + p0) * PP + tid]);
        *(bf16x8*)(phi_b[0] + tid * 8) = pv;
        BC_l[0][tid] = Bqt[((size_t)b * PP + p0) * NCH + tid];
    } else if (tid < 192) {
        rs_row[0][tid - 128] = RSvT[((size_t)(b * PP + p0)) * 64 + tid - 128];
    }
    __syncthreads();

    for (int r = 0; r < 8; ++r) {
        int cur = r & 1, nxt = cur ^ 1;
        int p = p0 + r;
        float pfv[8]; float bcn = 0.f; float rsn = 0.f;
        if (r < 7) {
            if (tid < 128) {
                #pragma unroll
                for (int ci = 0; ci < 8; ++ci)
                    pfv[ci] = phi[((size_t)(b * CIN + ci) * PP + p + 1) * PP + tid];
                bcn = Bqt[((size_t)b * PP + p + 1) * NCH + tid];
            } else if (tid < 192) {
                rsn = RSvT[((size_t)(b * PP + p + 1)) * 64 + tid - 128];
            }
        }
        const unsigned short* pb = phi_b[cur];
        #pragma unroll
        for (int pt = 0; pt < 8; ++pt) {
            int pix = pt * 16 + lr;
            bf16x8 bfr1 = {0, 0, 0, 0, 0, 0, 0, 0};
            if (lg == 0) bfr1 = *(const bf16x8*)(pb + pix * 8);
            f32x4 a = __builtin_amdgcn_mfma_f32_16x16x32_bf16(w1fr, bfr1, binit, 0, 0, 0);
            uint2 u;
            u.x = pk2(fmaxf(a.x, 0.f), fmaxf(a.y, 0.f));
            u.y = pk2(fmaxf(a.z, 0.f), fmaxf(a.w, 0.f));
            *(uint2*)((char*)t_l + SWZB(pix, c0 * 2)) = u;
        }
        __syncthreads();                     // (A) t_l ready
        bf16x8 afr[4];
        #pragma unroll
        for (int ks = 0; ks < 4; ++ks)
            afr[ks] = *(const bf16x8*)((char*)t_l + SWZB(wv * 16 + lr, ks * 64 + lg * 16));
        __syncthreads();                     // (B) afr reads done -> t_l reusable
        #pragma unroll
        for (int nt = 0; nt < 8; ++nt) {
            int o = nt * 16 + lr;
            bf16x8 bfr[4];
            #pragma unroll
            for (int ks = 0; ks < 4; ++ks)
                bfr[ks] = *(const bf16x8*)((char*)w3_l + SWZB(o, ks * 64 + lg * 16));
            f32x4 acc = apr[nt] + BC_l[cur][o];
            #pragma unroll
            for (int ks = 0; ks < 4; ++ks)
                acc = __builtin_amdgcn_mfma_f32_16x16x32_bf16(afr[ks], bfr[ks], acc, 0, 0, 0);
            uint2 u;
            u.x = pk2(fmaxf(acc.x, 0.f), fmaxf(acc.y, 0.f));
            u.y = pk2(fmaxf(acc.z, 0.f), fmaxf(acc.w, 0.f));
            *(uint2*)((char*)t_l + SWZB(o, q0 * 2)) = u;
        }
        if (r < 7) {
            if (tid < 128) {
                bf16x8 pv;
                #pragma unroll
                for (int ci = 0; ci < 8; ++ci) pv[ci] = (short)f2bf(pfv[ci]);
                *(bf16x8*)(phi_b[nxt] + tid * 8) = pv;
                BC_l[nxt][tid] = bcn;
            } else if (tid < 192) {
                rs_row[nxt][tid - 128] = rsn;
            }
        }
        __syncthreads();                     // (C) v_l + next-row data ready
        #pragma unroll
        for (int i = 0; i < 4; ++i) {
            int k = tid + i * 512;
            int o = k >> 4, j = k & 15;
            int g = o >> 5;
            bf16x8 u = *(const bf16x8*)((char*)t_l + SWZB(o, j * 16));
            float rp = (g >= 2) ? rs_row[cur][o - 64] : 0.f;
            float o8[8];
            #pragma unroll
            for (int e = 0; e < 8; ++e) {
                float v = bf2f((unsigned short)u[e]);
                float cq = (e < 4) ? ((const float*)&csr[i][0])[e]
                                   : ((const float*)&csr[i][1])[e - 4];
                float rr;
                if (g == 0)      rr = v;
                else if (g == 1) rr = (cq - v) * (1.f / 3.f);
                else if (g == 2) rr = (rp - v) * (1.f / 3.f);
                else             rr = ((sjr[i] - rp) - cq + v) * (1.f / 9.f);
                o8[e] = rr;
            }
            f32x4 lo = {o8[0], o8[1], o8[2], o8[3]};
            f32x4 hi = {o8[4], o8[5], o8[6], o8[7]};
            float* dst = out + ((size_t)(b * NCH + o) * PP + p) * PP + j * 8;
            *(f32x4*)dst       = lo;
            *(f32x4*)(dst + 4) = hi;
        }
        __syncthreads();                     // (D) v_l reads done before next GEMM1
    }
}

// ---------------------------------------------------------------------------
extern "C" void kernel_launch(void* const* d_in, const int* in_sizes, int n_in,
                              void* d_out, int out_size, void* d_ws, size_t ws_size,
                              hipStream_t stream) {
    (void)in_sizes; (void)n_in; (void)out_size; (void)ws_size;
    const float* phi = (const float*)d_in[0];
    const float* W1  = (const float*)d_in[1];
    const float* b1  = (const float*)d_in[2];
    const float* W3  = (const float*)d_in[3];
    const float* b3  = (const float*)d_in[4];
    float* out = (float*)d_out;

    char* ws = (char*)d_ws;
    size_t off = 0;
    float* RS1t = (float*)(ws + off); off += (size_t)BATCH * NCH * PP * 4;            // 2 MB
    float* CS1p = (float*)(ws + off); off += (size_t)BATCH * NSTRIP * NCH * PP * 4;   // 16 MB
    float* Ap   = (float*)(ws + off); off += (size_t)BATCH * NCH * PP * 4;            // 8 MB
    float* Bqt  = (float*)(ws + off); off += (size_t)BATCH * NCH * PP * 4;            // 8 MB
    unsigned short* W3bf = (unsigned short*)(ws + off); off += (size_t)NCH * NCH * 2; // 32 KB
    float* RSvT = (float*)(ws + off); off += (size_t)BATCH * PP * 64 * 4;             // 1 MB
    float* CSp  = (float*)(ws + off); off += (size_t)BATCH * KSTRIP * 64 * PP * 4;    // 16.8 MB
    float* CSv  = (float*)(ws + off); off += (size_t)BATCH * 64 * PP * 4;             // 1 MB
    float* Sb   = (float*)(ws + off); off += (size_t)BATCH * 32 * 4;                  // 4 KB

    k1_sums<<<BATCH * NSTRIP, 512, 0, stream>>>(phi, W1, b1, RS1t, CS1p);
    k1b_planes<<<BATCH * 4, 256, 0, stream>>>(W3, b3, RS1t, CS1p, Ap, Bqt, W3bf);
    k2a_sums<<<BATCH * KSTRIP, 512, 0, stream>>>(phi, W1, b1, W3bf, Ap, Bqt, RSvT, CSp);
    k2s_reduce<<<BATCH, 256, 0, stream>>>(CSp, RSvT, CSv, Sb);
    k2b_out<<<BATCH * KSTRIP, 512, 0, stream>>>(phi, W1, b1, W3bf, Ap, Bqt, RSvT, CSv, Sb, out);
}

// Round 15
// 186.439 us; speedup vs baseline: 1.2386x; 1.0292x over previous
//
#include <hip/hip_runtime.h>
#include <stdint.h>

#define BATCH 32
#define CIN   8
#define NCH   128   // 4*F_DIM
#define PP    128   // P
#define NSTRIP 8    // k1 strips per batch (16 p each)
#define KSTRIP 16   // k2 strips per batch (8 p each)

typedef __attribute__((ext_vector_type(8))) short    bf16x8;
typedef __attribute__((ext_vector_type(4))) float    f32x4;

__device__ __forceinline__ float bf2f(unsigned short u) {
    union { unsigned int i; float f; } x; x.i = ((unsigned int)u) << 16; return x.f;
}
__device__ __forceinline__ unsigned short f2bf(float f) {
    union { float f; unsigned int i; } x; x.f = f;
    unsigned int r = x.i + 0x7fffu + ((x.i >> 16) & 1u);
    return (unsigned short)(r >> 16);
}
__device__ __forceinline__ unsigned int pk2(float a, float b) {
    return (unsigned int)f2bf(a) | ((unsigned int)f2bf(b) << 16);
}

// Swizzled byte offset into a [128 rows][128 bf16] LDS tile (row = 256 B).
#define SWZB(row, cb) (((row) << 8) + ((cb) ^ (((row) & 7) << 4)))

// ---------------------------------------------------------------------------
// K1 (MFMA): RS1t[b][p][c] = sum_q t ; CS1p[b][strip][c][q] partial (R10).
// ---------------------------------------------------------------------------
__global__ __launch_bounds__(512, 4) void k1_sums(const float* __restrict__ phi,
        const float* __restrict__ W1, const float* __restrict__ b1,
        float* __restrict__ RS1t, float* __restrict__ CS1p) {
    __shared__ float cs_f[128 * 132];
    __shared__ unsigned short phi_b[2][1024];
    int bx = blockIdx.x;
    int b = bx >> 3, strip = bx & 7;
    int p0 = strip * 16;
    int tid = threadIdx.x;
    int wv = tid >> 6, l = tid & 63, lr = l & 15, lg = l >> 4;
    int c0 = wv * 16 + lg * 4;

    bf16x8 w1fr = {0, 0, 0, 0, 0, 0, 0, 0};
    if (lg == 0) {
        int cc = wv * 16 + lr;
        float4 wa = *(const float4*)(W1 + cc * 8);
        float4 wb = *(const float4*)(W1 + cc * 8 + 4);
        w1fr[0] = (short)f2bf(wa.x); w1fr[1] = (short)f2bf(wa.y);
        w1fr[2] = (short)f2bf(wa.z); w1fr[3] = (short)f2bf(wa.w);
        w1fr[4] = (short)f2bf(wb.x); w1fr[5] = (short)f2bf(wb.y);
        w1fr[6] = (short)f2bf(wb.z); w1fr[7] = (short)f2bf(wb.w);
    }
    f32x4 binit = {b1[c0], b1[c0 + 1], b1[c0 + 2], b1[c0 + 3]};
    if (tid < 128) {
        bf16x8 pv;
        #pragma unroll
        for (int ci = 0; ci < 8; ++ci)
            pv[ci] = (short)f2bf(phi[((size_t)(b * CIN + ci) * PP + p0) * PP + tid]);
        *(bf16x8*)(phi_b[0] + tid * 8) = pv;
    }
    __syncthreads();

    f32x4 cs_acc[8];
    #pragma unroll
    for (int i = 0; i < 8; ++i) { f32x4 z = {0.f, 0.f, 0.f, 0.f}; cs_acc[i] = z; }

    int cur = 0;
    for (int r = 0; r < 16; ++r) {
        int p = p0 + r;
        float pfv[8];
        if (r < 15 && tid < 128) {
            #pragma unroll
            for (int ci = 0; ci < 8; ++ci)
                pfv[ci] = phi[((size_t)(b * CIN + ci) * PP + p + 1) * PP + tid];
        }
        const unsigned short* pb = phi_b[cur];
        f32x4 rs4 = {0.f, 0.f, 0.f, 0.f};
        #pragma unroll
        for (int pt = 0; pt < 8; ++pt) {
            int pix = pt * 16 + lr;
            bf16x8 bfr1 = {0, 0, 0, 0, 0, 0, 0, 0};
            if (lg == 0) bfr1 = *(const bf16x8*)(pb + pix * 8);
            f32x4 a = __builtin_amdgcn_mfma_f32_16x16x32_bf16(w1fr, bfr1, binit, 0, 0, 0);
            f32x4 v = {fmaxf(a.x, 0.f), fmaxf(a.y, 0.f), fmaxf(a.z, 0.f), fmaxf(a.w, 0.f)};
            cs_acc[pt] += v;
            rs4 += v;
        }
        #pragma unroll
        for (int m = 1; m < 16; m <<= 1) {
            rs4.x += __shfl_xor(rs4.x, m);
            rs4.y += __shfl_xor(rs4.y, m);
            rs4.z += __shfl_xor(rs4.z, m);
            rs4.w += __shfl_xor(rs4.w, m);
        }
        if (lr == 0)
            *(f32x4*)(RS1t + ((size_t)b * PP + p) * NCH + c0) = rs4;
        if (r < 15 && tid < 128) {
            bf16x8 pv;
            #pragma unroll
            for (int ci = 0; ci < 8; ++ci) pv[ci] = (short)f2bf(pfv[ci]);
            *(bf16x8*)(phi_b[cur ^ 1] + tid * 8) = pv;
        }
        __syncthreads();
        cur ^= 1;
    }
    #pragma unroll
    for (int pt = 0; pt < 8; ++pt) {
        f32x4 v = cs_acc[pt];
        int q = pt * 16 + lr;
        cs_f[(c0 + 0) * 132 + q] = v.x;
        cs_f[(c0 + 1) * 132 + q] = v.y;
        cs_f[(c0 + 2) * 132 + q] = v.z;
        cs_f[(c0 + 3) * 132 + q] = v.w;
    }
    __syncthreads();
    float* dstp = CS1p + (size_t)(b * NSTRIP + strip) * NCH * PP;
    for (int k = tid; k < 16384; k += 512) {
        int cc = k >> 7, q = k & 127;
        dstp[k] = cs_f[cc * 132 + q];
    }
}

// ---------------------------------------------------------------------------
// K1b: Ap[b][o][q], Bqt[b][p][o] (with Cc folded in), W3bf (block 0).
// ---------------------------------------------------------------------------
__global__ __launch_bounds__(256) void k1b_planes(const float* __restrict__ W3,
        const float* __restrict__ b3, const float* __restrict__ RS1t,
        const float* __restrict__ CS1p, float* __restrict__ Ap,
        float* __restrict__ Bqt, unsigned short* __restrict__ W3bf) {
    int bx = blockIdx.x;
    int b = bx >> 2, og = bx & 3;
    int tid = threadIdx.x;
    __shared__ float cs_g[64][132];
    __shared__ float rs_g[64][132];
    __shared__ float s1_96[32];
    for (int k = tid; k < 64 * 128; k += 256) {
        int r = k >> 7, q = k & 127;
        int ch_c = (r < 32) ? (32 + r) : (64 + r);
        float s = 0.f;
        #pragma unroll
        for (int s8 = 0; s8 < NSTRIP; ++s8)
            s += CS1p[((size_t)(b * NSTRIP + s8) * NCH + ch_c) * PP + q];
        cs_g[r][q] = s;
    }
    for (int k = tid; k < 64 * 128; k += 256) {
        int p = k >> 6, r = k & 63;
        rs_g[r][p] = RS1t[((size_t)b * PP + p) * NCH + 64 + r];
    }
    __syncthreads();
    if (tid < 32) {
        float s = 0.f;
        for (int q = 0; q < 128; ++q) s += cs_g[32 + tid][q];
        s1_96[tid] = s;
    }
    int o = og * 32 + (tid >> 3), qh = tid & 7;
    {
        float wa[64];
        #pragma unroll
        for (int r = 0; r < 64; ++r)
            wa[r] = (r < 32) ? W3[o * NCH + 32 + r] * (1.f / 3.f)
                             : -W3[o * NCH + 64 + r] * (1.f / 9.f);
        #pragma unroll
        for (int j = 0; j < 4; ++j) {
            int q = qh * 16 + j * 4;
            float4 a = {0.f, 0.f, 0.f, 0.f};
            #pragma unroll
            for (int r = 0; r < 64; ++r) {
                float4 cv = *(const float4*)&cs_g[r][q];
                a.x = fmaf(wa[r], cv.x, a.x);
                a.y = fmaf(wa[r], cv.y, a.y);
                a.z = fmaf(wa[r], cv.z, a.z);
                a.w = fmaf(wa[r], cv.w, a.w);
            }
            *(float4*)&Ap[((size_t)b * NCH + o) * PP + q] = a;
        }
    }
    __syncthreads();
    float cc = b3[o];
    #pragma unroll
    for (int r = 0; r < 32; ++r)
        cc = fmaf(W3[o * NCH + 96 + r] * (1.f / 9.f), s1_96[r], cc);
    {
        float wb[64];
        #pragma unroll
        for (int r = 0; r < 64; ++r)
            wb[r] = (r < 32) ? W3[o * NCH + 64 + r] * (1.f / 3.f)
                             : -W3[o * NCH + 64 + r] * (1.f / 9.f);
        #pragma unroll
        for (int j = 0; j < 4; ++j) {
            int p4 = qh * 16 + j * 4;
            float4 a = {0.f, 0.f, 0.f, 0.f};
            #pragma unroll
            for (int r = 0; r < 64; ++r) {
                float4 rv = *(const float4*)&rs_g[r][p4];
                a.x = fmaf(wb[r], rv.x, a.x);
                a.y = fmaf(wb[r], rv.y, a.y);
                a.z = fmaf(wb[r], rv.z, a.z);
                a.w = fmaf(wb[r], rv.w, a.w);
            }
            Bqt[((size_t)b * PP + p4 + 0) * NCH + o] = a.x + cc;
            Bqt[((size_t)b * PP + p4 + 1) * NCH + o] = a.y + cc;
            Bqt[((size_t)b * PP + p4 + 2) * NCH + o] = a.z + cc;
            Bqt[((size_t)b * PP + p4 + 3) * NCH + o] = a.w + cc;
        }
    }
    if (bx == 0) {
        for (int i = 0; i < 16; ++i) {
            int k = tid + i * 256;
            float4 w = *(const float4*)(W3 + k * 4);
            int c0 = (k * 4) & 127;
            float sc = (c0 < 32) ? 1.f : ((c0 < 96) ? (-1.f / 3.f) : (1.f / 9.f));
            unsigned int lo = pk2(w.x * sc, w.y * sc);
            unsigned int hi = pk2(w.z * sc, w.w * sc);
            uint2 u = {lo, hi};
            *(uint2*)(W3bf + k * 4) = u;
        }
    }
}

// ---------------------------------------------------------------------------
// K2a: v-SUMS pass, NO v materialization (identical to R14).
// ---------------------------------------------------------------------------
__global__ __launch_bounds__(512) void k2a_sums(const float* __restrict__ phi,
        const float* __restrict__ W1, const float* __restrict__ b1,
        const unsigned short* __restrict__ W3bf,
        const float* __restrict__ Ap, const float* __restrict__ Bqt,
        float* __restrict__ RSvT, float* __restrict__ CSp) {
    int bx = blockIdx.x;
    int b = bx >> 4, strip = bx & 15;
    int p0 = strip * 8;
    __shared__ unsigned short w3_l[16384];
    __shared__ unsigned short t_l[16384];
    __shared__ unsigned short phi_b[2][1024];
    __shared__ float BC_l[2][128];
    __shared__ float rs_part[8][64];
    int tid = threadIdx.x;
    int wv = tid >> 6, l = tid & 63, lr = l & 15, lg = l >> 4;
    int q0 = wv * 16 + lg * 4;
    int c0 = q0;

    #pragma unroll
    for (int i = 0; i < 4; ++i) {
        int k = tid + i * 512;
        int o = k >> 4, cb = (k & 15) * 16;
        bf16x8 v = *(const bf16x8*)(W3bf + k * 8);
        *(bf16x8*)((char*)w3_l + SWZB(o, cb)) = v;
    }
    bf16x8 w1fr = {0, 0, 0, 0, 0, 0, 0, 0};
    if (lg == 0) {
        int cc = wv * 16 + lr;
        float4 wa = *(const float4*)(W1 + cc * 8);
        float4 wb = *(const float4*)(W1 + cc * 8 + 4);
        w1fr[0] = (short)f2bf(wa.x); w1fr[1] = (short)f2bf(wa.y);
        w1fr[2] = (short)f2bf(wa.z); w1fr[3] = (short)f2bf(wa.w);
        w1fr[4] = (short)f2bf(wb.x); w1fr[5] = (short)f2bf(wb.y);
        w1fr[6] = (short)f2bf(wb.z); w1fr[7] = (short)f2bf(wb.w);
    }
    f32x4 binit = {b1[c0], b1[c0 + 1], b1[c0 + 2], b1[c0 + 3]};
    f32x4 apr[6];
    #pragma unroll
    for (int nt = 2; nt < 8; ++nt)
        apr[nt - 2] = *(const f32x4*)(Ap + ((size_t)(b * NCH + nt * 16 + lr)) * PP + q0);
    if (tid < 128) {
        bf16x8 pv;
        #pragma unroll
        for (int ci = 0; ci < 8; ++ci)
            pv[ci] = (short)f2bf(phi[((size_t)(b * CIN + ci) * PP + p0) * PP + tid]);
        *(bf16x8*)(phi_b[0] + tid * 8) = pv;
        BC_l[0][tid] = Bqt[((size_t)b * PP + p0) * NCH + tid];
    }
    __syncthreads();

    f32x4 cs1a = {0.f,0.f,0.f,0.f}, cs1b = {0.f,0.f,0.f,0.f};
    f32x4 cs3a = {0.f,0.f,0.f,0.f}, cs3b = {0.f,0.f,0.f,0.f};

    for (int r = 0; r < 8; ++r) {
        int cur = r & 1, nxt = cur ^ 1;
        int p = p0 + r;
        float pfv[8]; float bcn = 0.f;
        if (r < 7 && tid < 128) {
            #pragma unroll
            for (int ci = 0; ci < 8; ++ci)
                pfv[ci] = phi[((size_t)(b * CIN + ci) * PP + p + 1) * PP + tid];
            bcn = Bqt[((size_t)b * PP + p + 1) * NCH + tid];
        }
        const unsigned short* pb = phi_b[cur];
        #pragma unroll
        for (int pt = 0; pt < 8; ++pt) {
            int pix = pt * 16 + lr;
            bf16x8 bfr1 = {0, 0, 0, 0, 0, 0, 0, 0};
            if (lg == 0) bfr1 = *(const bf16x8*)(pb + pix * 8);
            f32x4 a = __builtin_amdgcn_mfma_f32_16x16x32_bf16(w1fr, bfr1, binit, 0, 0, 0);
            uint2 u;
            u.x = pk2(fmaxf(a.x, 0.f), fmaxf(a.y, 0.f));
            u.y = pk2(fmaxf(a.z, 0.f), fmaxf(a.w, 0.f));
            *(uint2*)((char*)t_l + SWZB(pix, c0 * 2)) = u;
        }
        __syncthreads();                     // (A) t_l ready
        bf16x8 afr[4];
        #pragma unroll
        for (int ks = 0; ks < 4; ++ks)
            afr[ks] = *(const bf16x8*)((char*)t_l + SWZB(wv * 16 + lr, ks * 64 + lg * 16));
        #pragma unroll
        for (int nt = 2; nt < 8; ++nt) {
            int o = nt * 16 + lr;
            bf16x8 bfr[4];
            #pragma unroll
            for (int ks = 0; ks < 4; ++ks)
                bfr[ks] = *(const bf16x8*)((char*)w3_l + SWZB(o, ks * 64 + lg * 16));
            f32x4 acc = apr[nt - 2] + BC_l[cur][o];
            #pragma unroll
            for (int ks = 0; ks < 4; ++ks)
                acc = __builtin_amdgcn_mfma_f32_16x16x32_bf16(afr[ks], bfr[ks], acc, 0, 0, 0);
            f32x4 v = {fmaxf(acc.x, 0.f), fmaxf(acc.y, 0.f), fmaxf(acc.z, 0.f), fmaxf(acc.w, 0.f)};
            if (nt == 2) cs1a += v;
            else if (nt == 3) cs1b += v;
            else if (nt == 6) cs3a += v;
            else if (nt == 7) cs3b += v;
            if (nt >= 4) {
                float rsv = v.x + v.y + v.z + v.w;
                rsv += __shfl_xor(rsv, 16);
                rsv += __shfl_xor(rsv, 32);
                if (lg == 0) rs_part[wv][(nt - 4) * 16 + lr] = rsv;
            }
        }
        if (r < 7 && tid < 128) {
            bf16x8 pv;
            #pragma unroll
            for (int ci = 0; ci < 8; ++ci) pv[ci] = (short)f2bf(pfv[ci]);
            *(bf16x8*)(phi_b[nxt] + tid * 8) = pv;
            BC_l[nxt][tid] = bcn;
        }
        __syncthreads();                     // (B) afr reads + rs_part ready
        if (tid < 64) {
            float s = 0.f;
            #pragma unroll
            for (int w8 = 0; w8 < 8; ++w8) s += rs_part[w8][tid];
            RSvT[((size_t)(b * PP + p)) * 64 + tid] = s;
        }
    }
    {
        float* dst = CSp + ((size_t)(b * KSTRIP + strip)) * 64 * PP;
        *(f32x4*)(dst + (size_t)(lr)      * PP + q0) = cs1a;   // ch 32+lr
        *(f32x4*)(dst + (size_t)(16 + lr) * PP + q0) = cs1b;   // ch 48+lr
        *(f32x4*)(dst + (size_t)(32 + lr) * PP + q0) = cs3a;   // ch 96+lr
        *(f32x4*)(dst + (size_t)(48 + lr) * PP + q0) = cs3b;   // ch 112+lr
    }
}

// ---------------------------------------------------------------------------
// K2s: PARALLELIZED strip reduction.  Grid 32 b x 8 groups = 256 blocks.
// Each block reduces 8 jc rows (1024 CSv elements); Sb in grp==0 blocks.
// ---------------------------------------------------------------------------
__global__ __launch_bounds__(256) void k2s_reduce(const float* __restrict__ CSp,
        const float* __restrict__ RSvT, float* __restrict__ CSv,
        float* __restrict__ Sb) {
    int bx = blockIdx.x;
    int b = bx >> 3, grp = bx & 7;
    int tid = threadIdx.x;
    #pragma unroll
    for (int it = 0; it < 4; ++it) {
        int idx = grp * 1024 + it * 256 + tid;      // jc*PP + q, within [0, 8192)
        float s = 0.f;
        #pragma unroll
        for (int st = 0; st < KSTRIP; ++st)
            s += CSp[((size_t)(b * KSTRIP + st)) * 64 * PP + idx];
        CSv[(size_t)b * 64 * PP + idx] = s;
    }
    if (grp == 0 && tid < 32) {
        float s = 0.f;
        for (int p = 0; p < PP; ++p) s += RSvT[((size_t)(b * PP + p)) * 64 + 32 + tid];
        Sb[b * 32 + tid] = s;
    }
}

// ---------------------------------------------------------------------------
// K2b: OUTPUT pass (identical to R14).
// ---------------------------------------------------------------------------
__global__ __launch_bounds__(512) void k2b_out(const float* __restrict__ phi,
        const float* __restrict__ W1, const float* __restrict__ b1,
        const unsigned short* __restrict__ W3bf,
        const float* __restrict__ Ap, const float* __restrict__ Bqt,
        const float* __restrict__ RSvT, const float* __restrict__ CSv,
        const float* __restrict__ Sb, float* __restrict__ out) {
    int bx = blockIdx.x;
    int b = bx >> 4, strip = bx & 15;
    int p0 = strip * 8;
    __shared__ unsigned short w3_l[16384];
    __shared__ unsigned short t_l[16384];
    __shared__ unsigned short phi_b[2][1024];
    __shared__ float BC_l[2][128];
    __shared__ float rs_row[2][64];
    int tid = threadIdx.x;
    int wv = tid >> 6, l = tid & 63, lr = l & 15, lg = l >> 4;
    int q0 = wv * 16 + lg * 4;
    int c0 = q0;

    #pragma unroll
    for (int i = 0; i < 4; ++i) {
        int k = tid + i * 512;
        int o = k >> 4, cb = (k & 15) * 16;
        bf16x8 v = *(const bf16x8*)(W3bf + k * 8);
        *(bf16x8*)((char*)w3_l + SWZB(o, cb)) = v;
    }
    bf16x8 w1fr = {0, 0, 0, 0, 0, 0, 0, 0};
    if (lg == 0) {
        int cc = wv * 16 + lr;
        float4 wa = *(const float4*)(W1 + cc * 8);
        float4 wb = *(const float4*)(W1 + cc * 8 + 4);
        w1fr[0] = (short)f2bf(wa.x); w1fr[1] = (short)f2bf(wa.y);
        w1fr[2] = (short)f2bf(wa.z); w1fr[3] = (short)f2bf(wa.w);
        w1fr[4] = (short)f2bf(wb.x); w1fr[5] = (short)f2bf(wb.y);
        w1fr[6] = (short)f2bf(wb.z); w1fr[7] = (short)f2bf(wb.w);
    }
    f32x4 binit = {b1[c0], b1[c0 + 1], b1[c0 + 2], b1[c0 + 3]};
    f32x4 apr[8];
    #pragma unroll
    for (int nt = 0; nt < 8; ++nt)
        apr[nt] = *(const f32x4*)(Ap + ((size_t)(b * NCH + nt * 16 + lr)) * PP + q0);
    f32x4 csr[4][2];
    float sjr[4];
    #pragma unroll
    for (int i = 0; i < 4; ++i) {
        int k = tid + i * 512;
        int o = k >> 4, j = k & 15;
        int g = o >> 5;
        f32x4 z = {0.f, 0.f, 0.f, 0.f};
        csr[i][0] = z; csr[i][1] = z; sjr[i] = 0.f;
        if (g == 1) {
            int jc = o - 32;
            csr[i][0] = *(const f32x4*)(CSv + ((size_t)b * 64 + jc) * PP + j * 8);
            csr[i][1] = *(const f32x4*)(CSv + ((size_t)b * 64 + jc) * PP + j * 8 + 4);
        } else if (g == 3) {
            int jc = 32 + (o - 96);
            csr[i][0] = *(const f32x4*)(CSv + ((size_t)b * 64 + jc) * PP + j * 8);
            csr[i][1] = *(const f32x4*)(CSv + ((size_t)b * 64 + jc) * PP + j * 8 + 4);
            sjr[i] = Sb[b * 32 + (o - 96)];
        }
    }
    if (tid < 128) {
        bf16x8 pv;
        #pragma unroll
        for (int ci = 0; ci < 8; ++ci)
            pv[ci] = (short)f2bf(phi[((size_t)(b * CIN + ci) * PP + p0) * PP + tid]);
        *(bf16x8*)(phi_b[0] + tid * 8) = pv;
        BC_l[0][tid] = Bqt[((size_t)b * PP + p0) * NCH + tid];
    } else if (tid < 192) {
        rs_row[0][tid - 128] = RSvT[((size_t)(b * PP + p0)) * 64 + tid - 128];
    }
    __syncthreads();

    for (int r = 0; r < 8; ++r) {
        int cur = r & 1, nxt = cur ^ 1;
        int p = p0 + r;
        float pfv[8]; float bcn = 0.f; float rsn = 0.f;
        if (r < 7) {
            if (tid < 128) {
                #pragma unroll
                for (int ci = 0; ci < 8; ++ci)
                    pfv[ci] = phi[((size_t)(b * CIN + ci) * PP + p + 1) * PP + tid];
                bcn = Bqt[((size_t)b * PP + p + 1) * NCH + tid];
            } else if (tid < 192) {
                rsn = RSvT[((size_t)(b * PP + p + 1)) * 64 + tid - 128];
            }
        }
        const unsigned short* pb = phi_b[cur];
        #pragma unroll
        for (int pt = 0; pt < 8; ++pt) {
            int pix = pt * 16 + lr;
            bf16x8 bfr1 = {0, 0, 0, 0, 0, 0, 0, 0};
            if (lg == 0) bfr1 = *(const bf16x8*)(pb + pix * 8);
            f32x4 a = __builtin_amdgcn_mfma_f32_16x16x32_bf16(w1fr, bfr1, binit, 0, 0, 0);
            uint2 u;
            u.x = pk2(fmaxf(a.x, 0.f), fmaxf(a.y, 0.f));
            u.y = pk2(fmaxf(a.z, 0.f), fmaxf(a.w, 0.f));
            *(uint2*)((char*)t_l + SWZB(pix, c0 * 2)) = u;
        }
        __syncthreads();                     // (A) t_l ready
        bf16x8 afr[4];
        #pragma unroll
        for (int ks = 0; ks < 4; ++ks)
            afr[ks] = *(const bf16x8*)((char*)t_l + SWZB(wv * 16 + lr, ks * 64 + lg * 16));
        __syncthreads();                     // (B) afr reads done -> t_l reusable
        #pragma unroll
        for (int nt = 0; nt < 8; ++nt) {
            int o = nt * 16 + lr;
            bf16x8 bfr[4];
            #pragma unroll
            for (int ks = 0; ks < 4; ++ks)
                bfr[ks] = *(const bf16x8*)((char*)w3_l + SWZB(o, ks * 64 + lg * 16));
            f32x4 acc = apr[nt] + BC_l[cur][o];
            #pragma unroll
            for (int ks = 0; ks < 4; ++ks)
                acc = __builtin_amdgcn_mfma_f32_16x16x32_bf16(afr[ks], bfr[ks], acc, 0, 0, 0);
            uint2 u;
            u.x = pk2(fmaxf(acc.x, 0.f), fmaxf(acc.y, 0.f));
            u.y = pk2(fmaxf(acc.z, 0.f), fmaxf(acc.w, 0.f));
            *(uint2*)((char*)t_l + SWZB(o, q0 * 2)) = u;
        }
        if (r < 7) {
            if (tid < 128) {
                bf16x8 pv;
                #pragma unroll
                for (int ci = 0; ci < 8; ++ci) pv[ci] = (short)f2bf(pfv[ci]);
                *(bf16x8*)(phi_b[nxt] + tid * 8) = pv;
                BC_l[nxt][tid] = bcn;
            } else if (tid < 192) {
                rs_row[nxt][tid - 128] = rsn;
            }
        }
        __syncthreads();                     // (C) v_l + next-row data ready
        #pragma unroll
        for (int i = 0; i < 4; ++i) {
            int k = tid + i * 512;
            int o = k >> 4, j = k & 15;
            int g = o >> 5;
            bf16x8 u = *(const bf16x8*)((char*)t_l + SWZB(o, j * 16));
            float rp = (g >= 2) ? rs_row[cur][o - 64] : 0.f;
            float o8[8];
            #pragma unroll
            for (int e = 0; e < 8; ++e) {
                float v = bf2f((unsigned short)u[e]);
                float cq = (e < 4) ? ((const float*)&csr[i][0])[e]
                                   : ((const float*)&csr[i][1])[e - 4];
                float rr;
                if (g == 0)      rr = v;
                else if (g == 1) rr = (cq - v) * (1.f / 3.f);
                else if (g == 2) rr = (rp - v) * (1.f / 3.f);
                else             rr = ((sjr[i] - rp) - cq + v) * (1.f / 9.f);
                o8[e] = rr;
            }
            f32x4 lo = {o8[0], o8[1], o8[2], o8[3]};
            f32x4 hi = {o8[4], o8[5], o8[6], o8[7]};
            float* dst = out + ((size_t)(b * NCH + o) * PP + p) * PP + j * 8;
            *(f32x4*)dst       = lo;
            *(f32x4*)(dst + 4) = hi;
        }
        __syncthreads();                     // (D) v_l reads done before next GEMM1
    }
}

// ---------------------------------------------------------------------------
extern "C" void kernel_launch(void* const* d_in, const int* in_sizes, int n_in,
                              void* d_out, int out_size, void* d_ws, size_t ws_size,
                              hipStream_t stream) {
    (void)in_sizes; (void)n_in; (void)out_size; (void)ws_size;
    const float* phi = (const float*)d_in[0];
    const float* W1  = (const float*)d_in[1];
    const float* b1  = (const float*)d_in[2];
    const float* W3  = (const float*)d_in[3];
    const float* b3  = (const float*)d_in[4];
    float* out = (float*)d_out;

    char* ws = (char*)d_ws;
    size_t off = 0;
    float* RS1t = (float*)(ws + off); off += (size_t)BATCH * NCH * PP * 4;            // 2 MB
    float* CS1p = (float*)(ws + off); off += (size_t)BATCH * NSTRIP * NCH * PP * 4;   // 16 MB
    float* Ap   = (float*)(ws + off); off += (size_t)BATCH * NCH * PP * 4;            // 8 MB
    float* Bqt  = (float*)(ws + off); off += (size_t)BATCH * NCH * PP * 4;            // 8 MB
    unsigned short* W3bf = (unsigned short*)(ws + off); off += (size_t)NCH * NCH * 2; // 32 KB
    float* RSvT = (float*)(ws + off); off += (size_t)BATCH * PP * 64 * 4;             // 1 MB
    float* CSp  = (float*)(ws + off); off += (size_t)BATCH * KSTRIP * 64 * PP * 4;    // 16.8 MB
    float* CSv  = (float*)(ws + off); off += (size_t)BATCH * 64 * PP * 4;             // 1 MB
    float* Sb   = (float*)(ws + off); off += (size_t)BATCH * 32 * 4;                  // 4 KB

    k1_sums<<<BATCH * NSTRIP, 512, 0, stream>>>(phi, W1, b1, RS1t, CS1p);
    k1b_planes<<<BATCH * 4, 256, 0, stream>>>(W3, b3, RS1t, CS1p, Ap, Bqt, W3bf);
    k2a_sums<<<BATCH * KSTRIP, 512, 0, stream>>>(phi, W1, b1, W3bf, Ap, Bqt, RSvT, CSp);
    k2s_reduce<<<BATCH * 8, 256, 0, stream>>>(CSp, RSvT, CSv, Sb);
    k2b_out<<<BATCH * KSTRIP, 512, 0, stream>>>(phi, W1, b1, W3bf, Ap, Bqt, RSvT, CSv, Sb, out);
}